// Round 10
// baseline (321.803 us; speedup 1.0000x reference)
//
#include <hip/hip_runtime.h>

typedef unsigned short u16;
typedef __bf16 bf16;
typedef __attribute__((ext_vector_type(8))) __bf16 bf16x8;
typedef __attribute__((ext_vector_type(4))) float f32x4;
typedef __attribute__((ext_vector_type(8))) unsigned short u16x8;
typedef unsigned long long u64;

__device__ __forceinline__ float bf2f(u16 h) {
  return __uint_as_float(((unsigned int)h) << 16);
}
__device__ __forceinline__ u16 f2bf(float f) {
  unsigned int u = __float_as_uint(f);
  return (u16)((u + 0x7fffu + ((u >> 16) & 1u)) >> 16);
}
__device__ __forceinline__ u16 ld_cv(const void* p, size_t i, int f32) {
  return f32 ? f2bf(((const float*)p)[i]) : ((const u16*)p)[i];
}
__device__ __forceinline__ float ld_f(const void* p, size_t i, int f32) {
  return f32 ? ((const float*)p)[i] : bf2f(((const u16*)p)[i]);
}
__device__ __forceinline__ void async16(const u16* g, u16* l) {
  __builtin_amdgcn_global_load_lds(
      (const __attribute__((address_space(1))) unsigned int*)g,
      (__attribute__((address_space(3))) unsigned int*)l, 16, 0, 0);
}
// raw v_exp_f32: D = 2^S0 (scale pre-folded into Q at the QKV epilogue)
__device__ __forceinline__ float exp2_raw(float x) {
  float r;
  asm("v_exp_f32 %0, %1" : "=v"(r) : "v"(x));
  return r;
}
// packed f32x2 -> bf16x2 (RNE); dst.lo = cvt(a), dst.hi = cvt(b)
__device__ __forceinline__ unsigned cvt_pk_bf16(float a, float b) {
  unsigned r;
  asm("v_cvt_pk_bf16_f32 %0, %1, %2" : "=v"(r) : "v"(a), "v"(b));
  return r;
}

// ---- mega-prep: weight transposes + fused dtype sniff --------------------
__global__ void prep_kernel(const u16* __restrict__ x,
                            const void* __restrict__ Wq, const void* __restrict__ Wk,
                            const void* __restrict__ Wv, const void* __restrict__ W1,
                            const void* __restrict__ W2,
                            u16* __restrict__ WTq, u16* __restrict__ W1T,
                            u16* __restrict__ W2T, int* __restrict__ flag) {
  __shared__ u16 tile[64][65];
  __shared__ int sm[4];
  const int tid = threadIdx.x;
  int me = 0;
#pragma unroll
  for (int j = 0; j < 4; j++) {
    const u16 v = x[(tid * 4 + j) * 2];
    const int e = (v >> 7) & 0xFF;
    me = me > e ? me : e;
  }
#pragma unroll
  for (int off = 32; off > 0; off >>= 1) {
    const int o = __shfl_down(me, off);
    me = me > o ? me : o;
  }
  if ((tid & 63) == 0) sm[tid >> 6] = me;
  __syncthreads();
  const int a01 = sm[0] > sm[1] ? sm[0] : sm[1];
  const int a23 = sm[2] > sm[3] ? sm[2] : sm[3];
  const int f = ((a01 > a23 ? a01 : a23) >= 140) ? 1 : 0;
  if (blockIdx.x == 0 && tid == 0) *flag = f;

  const int bid = blockIdx.x;
  const int lx = threadIdx.x & 63, ly = threadIdx.x >> 6;
  if (bid < 768) {
    const int bx = bid & 15, wh = bid >> 4;
    const int w = wh >> 4, hh = wh & 15;
    const int tr = bx * 64;
    const void* W = (w == 0) ? Wq : ((w == 1) ? Wk : Wv);
    const size_t hbase = (size_t)hh * 65536;
#pragma unroll
    for (int i = 0; i < 16; i++)
      tile[ly * 16 + i][lx] = ld_cv(W, hbase + (size_t)(tr + ly * 16 + i) * 64 + lx, f);
    __syncthreads();
#pragma unroll
    for (int i = 0; i < 16; i++)
      WTq[((size_t)(w * 1024 + hh * 64 + ly * 16 + i)) * 1024 + tr + lx] =
          tile[lx][ly * 16 + i];
  } else {
    const void* src;
    u16* dst;
    int R, C, tc, tr;
    if (bid < 1792) {
      const int j = bid - 768;
      src = W1; dst = W1T; R = 1024; C = 4096;
      tc = (j & 63) * 64; tr = (j >> 6) * 64;
    } else {
      const int j = bid - 1792;
      src = W2; dst = W2T; R = 4096; C = 1024;
      tc = (j & 15) * 64; tr = (j >> 4) * 64;
    }
#pragma unroll
    for (int i = 0; i < 16; i++)
      tile[ly * 16 + i][lx] = ld_cv(src, (size_t)(tr + ly * 16 + i) * C + tc + lx, f);
    __syncthreads();
#pragma unroll
    for (int i = 0; i < 16; i++)
      dst[(size_t)(tc + ly * 16 + i) * R + tr + lx] = tile[lx][ly * 16 + i];
  }
}

// ---------------- GEMM: C[m][n] = sum_k A[m][k] * BT[n][k] ----------------
// Chunk-XOR LDS swizzle (T2, rule #21). EPI==3: FFN2 split-K2 partials.
// EPI==0: Q output is pre-scaled by log2(e)/32 so attn uses raw v_exp_f32
// (exp(S/32) == 2^(S * 0.04508422)).
template <int EPI, int WR, int WC, bool MS>
__launch_bounds__(WR * WC * 64)
__global__ void gemm_bt(const u16* __restrict__ A, const u16* __restrict__ B,
                        int K, int KLD, int NX, int N,
                        const void* __restrict__ bias, const u16* __restrict__ res,
                        void* __restrict__ out,
                        u16* __restrict__ Qo, u16* __restrict__ Ko, u16* __restrict__ Vto,
                        const int* __restrict__ flag) {
  constexpr int BM = WR * 64, BN = WC * 64, T = WR * WC * 64;
  constexpr int RPA = T / 4;
  constexpr int RAH = BM / RPA;
  constexpr int RBH = BN / RPA;
  __shared__ __align__(16) u16 As[BM * 64];
  __shared__ __align__(16) u16 Bs[BN * 64];
  const int tid = threadIdx.x;
  const int bid = blockIdx.x;
  const int sxp = NX >> 3;
  const int xcd = bid & 7, j9 = bid >> 3;
  int m0, n0, koff = 0, khb = 0;
  if (EPI == 3) {
    m0 = (xcd * 4 + (j9 & 3)) * BM;
    n0 = ((j9 >> 2) & 7) * BN;
    khb = (j9 >> 5) & 1;
    koff = khb * K;
  } else if (MS) {
    m0 = (xcd * sxp + j9 % sxp) * BM;
    n0 = (j9 / sxp) * BN;
  } else {
    n0 = (xcd * sxp + j9 % sxp) * BN;
    m0 = (j9 / sxp) * BM;
  }
  const int wave = tid >> 6, lane = tid & 63;
  const int wm = (wave / WC) * 64, wn = (wave % WC) * 64;
  const int lm = lane & 15, lq = lane >> 4;
  const int fb = (EPI == 1 || EPI == 2) ? *flag : 0;

  const f32x4 zero = {0.f, 0.f, 0.f, 0.f};
  f32x4 acc[4][4];
#pragma unroll
  for (int i = 0; i < 4; i++)
#pragma unroll
    for (int j = 0; j < 4; j++) acc[i][j] = zero;

  const int ar = tid >> 2;
  const int ac = ((tid & 3) ^ ((tid >> 3) & 3)) * 8;
  const u16* Ag = A + (size_t)(m0 + ar) * KLD + koff + ac;
  const u16* Bg = B + (size_t)(n0 + ar) * KLD + koff + ac;
  u16* AsP = &As[tid * 8];
  u16* BsP = &Bs[tid * 8];
  const int rq = (lq ^ ((lm >> 1) & 3)) * 8;

  for (int k0 = 0; k0 < K; k0 += 64) {
#pragma unroll
    for (int hh = 0; hh < 2; hh++) {
#pragma unroll
      for (int c = 0; c < RAH; c++)
        async16(Ag + k0 + hh * 32 + (size_t)c * RPA * KLD,
                AsP + hh * BM * 32 + c * RPA * 32);
#pragma unroll
      for (int c = 0; c < RBH; c++)
        async16(Bg + k0 + hh * 32 + (size_t)c * RPA * KLD,
                BsP + hh * BN * 32 + c * RPA * 32);
    }
    __syncthreads();
    bf16x8 a0[4], a1[4], b0[4], b1[4];
#pragma unroll
    for (int i = 0; i < 4; i++) {
      a0[i] = *(const bf16x8*)&As[(wm + i * 16 + lm) * 32 + rq];
      a1[i] = *(const bf16x8*)&As[BM * 32 + (wm + i * 16 + lm) * 32 + rq];
    }
#pragma unroll
    for (int i = 0; i < 4; i++) {
      b0[i] = *(const bf16x8*)&Bs[(wn + i * 16 + lm) * 32 + rq];
      b1[i] = *(const bf16x8*)&Bs[BN * 32 + (wn + i * 16 + lm) * 32 + rq];
    }
#pragma unroll
    for (int i = 0; i < 4; i++)
#pragma unroll
      for (int j = 0; j < 4; j++) {
        acc[i][j] = __builtin_amdgcn_mfma_f32_16x16x32_bf16(a0[i], b0[j], acc[i][j], 0, 0, 0);
        acc[i][j] = __builtin_amdgcn_mfma_f32_16x16x32_bf16(a1[i], b1[j], acc[i][j], 0, 0, 0);
      }
    __syncthreads();
  }

  if (EPI == 0) {
#pragma unroll
    for (int i = 0; i < 4; i++) {
      const int row0 = m0 + wm + i * 16 + lq * 4;
      const int bb = row0 >> 11, t0 = row0 & 2047;
#pragma unroll
      for (int j = 0; j < 4; j++) {
        const int col = n0 + wn + j * 16 + lm;
        const int w = col >> 10, nn = col & 1023;
        const int hh = nn >> 6, e = nn & 63;
        if (w == 2) {
          ushort4 v4;
          v4.x = f2bf(acc[i][j][0]);
          v4.y = f2bf(acc[i][j][1]);
          v4.z = f2bf(acc[i][j][2]);
          v4.w = f2bf(acc[i][j][3]);
          *(ushort4*)&Vto[(((size_t)(bb * 16 + hh)) * 64 + e) * 2048 + t0] = v4;
        } else {
          u16* dst = (w == 0) ? Qo : Ko;
          const float qs = (w == 0) ? 0.04508422f : 1.0f;  // log2(e)/32 folded into Q
#pragma unroll
          for (int r = 0; r < 4; r++)
            dst[(((size_t)(bb * 16 + hh)) * 2048 + t0 + r) * 64 + e] =
                f2bf(acc[i][j][r] * qs);
        }
      }
    }
  } else if (EPI == 3) {
    u16* P = khb ? Ko : Qo;
#pragma unroll
    for (int i = 0; i < 4; i++) {
#pragma unroll
      for (int r = 0; r < 4; r++) {
        const int row = m0 + wm + i * 16 + lq * 4 + r;
#pragma unroll
        for (int j = 0; j < 4; j++) {
          const int col = n0 + wn + j * 16 + lm;
          P[(size_t)row * N + col] = f2bf(acc[i][j][r]);
        }
      }
    }
  } else {
#pragma unroll
    for (int i = 0; i < 4; i++) {
#pragma unroll
      for (int r = 0; r < 4; r++) {
        const int row = m0 + wm + i * 16 + lq * 4 + r;
#pragma unroll
        for (int j = 0; j < 4; j++) {
          const int col = n0 + wn + j * 16 + lm;
          const float c = acc[i][j][r];
          if (EPI == 1) {
            const float v = c + ld_f(bias, col, fb);
            ((u16*)out)[(size_t)row * N + col] = f2bf(v > 0.f ? v : 0.f);
          } else {
            const float v = c + ld_f(bias, col, fb) + bf2f(res[(size_t)row * N + col]);
            if (fb)
              ((float*)out)[(size_t)row * N + col] = v;
            else
              ((u16*)out)[(size_t)row * N + col] = f2bf(v);
          }
        }
      }
    }
  }
}

// ---------------- FFN2 split-K reduce: out = P0 + P1 + bias + res ----------
__launch_bounds__(256)
__global__ void ffn2_reduce(const u16* __restrict__ P0, const u16* __restrict__ P1,
                            const void* __restrict__ bias, const u16* __restrict__ res,
                            void* __restrict__ out, const int* __restrict__ flag) {
  const int f = *flag;
  const size_t i0 = ((size_t)blockIdx.x * 256 + threadIdx.x) * 8;
  const int col = (int)(i0 & 1023);
  const u16x8 a8 = *(const u16x8*)(P0 + i0);
  const u16x8 b8 = *(const u16x8*)(P1 + i0);
  const u16x8 r8 = *(const u16x8*)(res + i0);
  float v[8];
#pragma unroll
  for (int k = 0; k < 8; k++)
    v[k] = bf2f(a8[k]) + bf2f(b8[k]) + ld_f(bias, col + k, f) + bf2f(r8[k]);
  if (f) {
    float4 o0 = {v[0], v[1], v[2], v[3]};
    float4 o1 = {v[4], v[5], v[6], v[7]};
    *(float4*)((float*)out + i0) = o0;
    *(float4*)((float*)out + i0 + 4) = o1;
  } else {
    u16x8 o8;
#pragma unroll
    for (int k = 0; k < 8; k++) o8[k] = f2bf(v[k]);
    *(u16x8*)((u16*)out + i0) = o8;
  }
}

// ---------------- MFMA flash attention v14: VALU-slimmed v9 ----------------
// v9 chassis (best of 6 structures, 16 waves/CU) with the per-tile VALU
// chain cut ~60%: (1) softmax scale folded into Q (QKV epilogue) -> raw
// v_exp_f32, no muls; (2) denominator l via ones-MFMA (A=ones: D[e][q] =
// sum_k P[k][q]) -- kills 32 adds/tile AND the shfl reduce; (3)
// v_cvt_pk_bf16_f32 pack (1 op/pair vs 3); (4) causal mask hoisted to the
// wave-uniform diagonal tile.
__launch_bounds__(256)
__global__ void attn_mfma(const u16* __restrict__ Q, const u16* __restrict__ K,
                          const u16* __restrict__ Vt, const void* __restrict__ xres,
                          const int* __restrict__ flag, u16* __restrict__ x2) {
  __shared__ __align__(16) unsigned char smem[35328];
  const int tid = threadIdx.x;
  const int wave = tid >> 6, lane = tid & 63;
  const int lm = lane & 15, quad = lane >> 4;
  const int bid = blockIdx.x;
  const int xcd = bid & 7, jj = bid >> 3;
  const int bh = xcd + 8 * (jj & 3);
  const int pair = jj >> 2;  // 0..31
  const int b = bh >> 4, h = bh & 15;
  const int f32in = *flag;

  u16* stw = (u16*)smem + wave * 4096;  // 8KB per wave
  u16* Ksw = stw;                        // [half][32 rows][4 chunks x 8]
  u16* Vsw = stw + 2048;                 // [64 rows][4 chunks x 8]
  float (*Olds)[32][68] = (float(*)[32][68])smem;          // 34816 B
  float (*Llds)[2][16] = (float(*)[2][16])(smem + 34816);  // 512 B

  const u16* Kbh = K + (size_t)bh * 131072;
  const u16* Vbh = Vt + (size_t)bh * 131072;
  const f32x4 zero = {0.f, 0.f, 0.f, 0.f};
  const int srow = lane >> 2;
  const int sch2 = (((lane & 3) ^ ((srow >> 1) & 3))) * 8;
  const int rk = (lm >> 1) & 3;

  union V8 { bf16x8 v; struct { u64 lo, hi; } q; };
  // all-ones bf16 A-fragment for the denominator MFMA
  u16x8 ob;
#pragma unroll
  for (int k = 0; k < 8; k++) ob[k] = 0x3F80;
  const bf16x8 ones = *(const bf16x8*)&ob;

#pragma unroll 1
  for (int phase = 0; phase < 2; phase++) {
    const int qb = phase ? (63 - pair) : pair;
    const int qw0 = qb * 32;

    bf16x8 qf[2][2];
#pragma unroll
    for (int s = 0; s < 2; s++) {
      const u16* Qp = Q + ((size_t)bh * 2048 + qw0 + s * 16 + lm) * 64 + quad * 8;
      qf[s][0] = *(const bf16x8*)Qp;
      qf[s][1] = *(const bf16x8*)(Qp + 32);
    }
    f32x4 ot[2][4];
    f32x4 al[2];
#pragma unroll
    for (int s = 0; s < 2; s++) {
#pragma unroll
      for (int j = 0; j < 4; j++) ot[s][j] = zero;
      al[s] = zero;
    }

    const int nt = qb + 1;
    const int si = (nt * wave) >> 2;
    const int ei = (nt * (wave + 1)) >> 2;

    for (int t = si; t < ei; t++) {
      const int ks = t * 32;
#pragma unroll
      for (int hh2 = 0; hh2 < 2; hh2++)
#pragma unroll
        for (int c = 0; c < 2; c++)
          async16(Kbh + (size_t)(ks + c * 16 + srow) * 64 + hh2 * 32 + sch2,
                  Ksw + hh2 * 1024 + c * 512 + lane * 8);
#pragma unroll
      for (int c = 0; c < 4; c++)
        async16(Vbh + (size_t)(c * 16 + srow) * 2048 + ks + sch2,
                Vsw + c * 512 + lane * 8);
      __builtin_amdgcn_s_waitcnt(0x0F70);  // vmcnt(0)

      f32x4 S[2][2];
#pragma unroll
      for (int s = 0; s < 2; s++)
#pragma unroll
        for (int hh = 0; hh < 2; hh++) {
          const bf16x8 k0 =
              *(const bf16x8*)&Ksw[(hh * 16 + lm) * 32 + (quad ^ rk) * 8];
          const bf16x8 k1 =
              *(const bf16x8*)&Ksw[1024 + (hh * 16 + lm) * 32 + (quad ^ rk) * 8];
          f32x4 a = zero;
          a = __builtin_amdgcn_mfma_f32_16x16x32_bf16(k0, qf[s][0], a, 0, 0, 0);
          a = __builtin_amdgcn_mfma_f32_16x16x32_bf16(k1, qf[s][1], a, 0, 0, 0);
          S[s][hh] = a;
        }
      const bool maskT = (t == qb);
#pragma unroll
      for (int s = 0; s < 2; s++) {
        float p[2][4];
#pragma unroll
        for (int hh = 0; hh < 2; hh++)
#pragma unroll
          for (int r = 0; r < 4; r++)
            p[hh][r] = exp2_raw(S[s][hh][r]);  // scale pre-folded into Q
        if (maskT) {  // wave-uniform: only the diagonal tile pays
#pragma unroll
          for (int hh = 0; hh < 2; hh++)
#pragma unroll
            for (int r = 0; r < 4; r++)
              if (hh * 16 + quad * 4 + r > s * 16 + lm) p[hh][r] = 0.f;
        }
        unsigned pk[4];
        pk[0] = cvt_pk_bf16(p[0][0], p[0][1]);
        pk[1] = cvt_pk_bf16(p[0][2], p[0][3]);
        pk[2] = cvt_pk_bf16(p[1][0], p[1][1]);
        pk[3] = cvt_pk_bf16(p[1][2], p[1][3]);
        const bf16x8 pf = *(const bf16x8*)pk;
        // denominator: D[e][q] = sum_k 1*P[k][q] (accumulates across tiles)
        al[s] = __builtin_amdgcn_mfma_f32_16x16x32_bf16(ones, pf, al[s], 0, 0, 0);
#pragma unroll
        for (int j = 0; j < 4; j++) {
          V8 vf;
          vf.q.lo = *(const u64*)&Vsw[(j * 16 + lm) * 32 +
                                      (((quad >> 1)) ^ rk) * 8 + (quad & 1) * 4];
          vf.q.hi = *(const u64*)&Vsw[(j * 16 + lm) * 32 +
                                      (((quad >> 1) | 2) ^ rk) * 8 + (quad & 1) * 4];
          ot[s][j] = __builtin_amdgcn_mfma_f32_16x16x32_bf16(vf.v, pf, ot[s][j], 0, 0, 0);
        }
      }
    }

    __syncthreads();  // ALL waves done staging/reading before Olds overwrite

#pragma unroll
    for (int s = 0; s < 2; s++)
#pragma unroll
      for (int j = 0; j < 4; j++)
        *(f32x4*)&Olds[wave][s * 16 + lm][j * 16 + quad * 4] = ot[s][j];
    if (quad == 0) {
      Llds[wave][0][lm] = al[0][0];  // full k-range sum via MFMA (no shfl)
      Llds[wave][1][lm] = al[1][0];
    }
    __syncthreads();
    const int q = tid >> 3;
    const int e0 = (tid & 7) * 8;
    f32x4 oa = zero, obv = zero;
#pragma unroll
    for (int w = 0; w < 4; w++) {
      oa += *(const f32x4*)&Olds[w][q][e0];
      obv += *(const f32x4*)&Olds[w][q][e0 + 4];
    }
    const float lt = Llds[0][q >> 4][q & 15] + Llds[1][q >> 4][q & 15] +
                     Llds[2][q >> 4][q & 15] + Llds[3][q >> 4][q & 15];
    const float linv = 1.f / lt;
    const size_t rowbase = ((size_t)(b * 2048 + qw0 + q)) * 1024 + h * 64 + e0;
    float xv[8];
    if (f32in) {
      const float* xf = (const float*)xres + rowbase;
      const float4 u0 = *(const float4*)xf;
      const float4 u1 = *(const float4*)(xf + 4);
      xv[0] = u0.x; xv[1] = u0.y; xv[2] = u0.z; xv[3] = u0.w;
      xv[4] = u1.x; xv[5] = u1.y; xv[6] = u1.z; xv[7] = u1.w;
    } else {
      const u16x8 u = *(const u16x8*)((const u16*)xres + rowbase);
#pragma unroll
      for (int k = 0; k < 8; k++) xv[k] = bf2f(u[k]);
    }
    u16x8 o8;
#pragma unroll
    for (int k = 0; k < 4; k++) o8[k] = f2bf(xv[k] + oa[k] * linv);
#pragma unroll
    for (int k = 0; k < 4; k++) o8[4 + k] = f2bf(xv[4 + k] + obv[k] * linv);
    *(u16x8*)&x2[rowbase] = o8;
    __syncthreads();
  }
}

// ---------------- LayerNorm (ddof=1, eps=1e-5), raw dual-dtype inputs ------
__launch_bounds__(256)
__global__ void ln_kernel(const void* __restrict__ x, const void* __restrict__ gamma,
                          const void* __restrict__ beta, u16* __restrict__ out,
                          const int* __restrict__ flag, int xraw) {
  const size_t row = blockIdx.x;
  const int tid = threadIdx.x;
  const int f = *flag;
  const int fx = xraw ? f : 0;
  float v0, v1, v2, v3;
  if (fx) {
    const float4 v = *((const float4*)x + row * 256 + tid);
    v0 = v.x; v1 = v.y; v2 = v.z; v3 = v.w;
  } else {
    const ushort4 u = *((const ushort4*)x + row * 256 + tid);
    v0 = bf2f(u.x); v1 = bf2f(u.y); v2 = bf2f(u.z); v3 = bf2f(u.w);
  }
  float s = v0 + v1 + v2 + v3;
  float sq = v0 * v0 + v1 * v1 + v2 * v2 + v3 * v3;
#pragma unroll
  for (int off = 32; off > 0; off >>= 1) {
    s += __shfl_down(s, off);
    sq += __shfl_down(sq, off);
  }
  __shared__ float ss[4], ssq[4];
  if ((tid & 63) == 0) { ss[tid >> 6] = s; ssq[tid >> 6] = sq; }
  __syncthreads();
  s = ss[0] + ss[1] + ss[2] + ss[3];
  sq = ssq[0] + ssq[1] + ssq[2] + ssq[3];
  const float mean = s * (1.f / 1024.f);
  const float var = (sq - 1024.f * mean * mean) * (1.f / 1023.f);
  const float rs = rsqrtf(var + 1e-5f);
  const int c0 = tid * 4;
  ushort4 o;
  o.x = f2bf(ld_f(gamma, c0 + 0, f) * (v0 - mean) * rs + ld_f(beta, c0 + 0, f));
  o.y = f2bf(ld_f(gamma, c0 + 1, f) * (v1 - mean) * rs + ld_f(beta, c0 + 1, f));
  o.z = f2bf(ld_f(gamma, c0 + 2, f) * (v2 - mean) * rs + ld_f(beta, c0 + 2, f));
  o.w = f2bf(ld_f(gamma, c0 + 3, f) * (v3 - mean) * rs + ld_f(beta, c0 + 3, f));
  *(ushort4*)&out[row * 1024 + tid * 4] = o;
}

extern "C" void kernel_launch(void* const* d_in, const int* in_sizes, int n_in,
                              void* d_out, int out_size, void* d_ws, size_t ws_size,
                              hipStream_t stream) {
  const void* x      = d_in[0];
  const void* Wq     = d_in[1];
  const void* Wk     = d_in[2];
  const void* Wv     = d_in[3];
  const void* W1     = d_in[4];
  const void* b1     = d_in[5];
  const void* W2     = d_in[6];
  const void* b2     = d_in[7];
  const void* gamma1 = d_in[8];
  const void* beta1  = d_in[9];
  const void* gamma2 = d_in[10];
  const void* beta2  = d_in[11];
  u16* ws = (u16*)d_ws;

  const size_t M4 = 4194304;
  u16* h   = ws;            // slot 0 (later: ff1 spans 0-3)
  u16* Qb  = ws + 1 * M4;   // slot 1
  u16* Kb  = ws + 2 * M4;   // slot 2
  u16* Vtb = ws + 3 * M4;   // slot 3
  u16* WTq = ws + 4 * M4;   // slot 4 (later: x2)
  u16* x2  = ws + 4 * M4;
  u16* h2  = ws + 5 * M4;   // slot 5 (later: FFN2 partial P0)
  u16* W1T = ws + 6 * M4;   // slot 6 (later: FFN2 partial P1)
  u16* W2T = ws + 7 * M4;   // slot 7
  u16* ff1 = ws;            // slots 0-3
  u16* P0  = ws + 5 * M4;   // bf16 partial kq=0 (h2 dead after FFN1)
  u16* P1  = ws + 6 * M4;   // bf16 partial kq=1 (W1T dead after FFN1)
  int* flag = (int*)(ws + 8 * M4 + 9216);

  // prep (with fused dtype sniff; block 0 publishes *flag)
  prep_kernel<<<2816, 256, 0, stream>>>((const u16*)x, Wq, Wk, Wv, W1, W2,
                                        WTq, W1T, W2T, flag);
  ln_kernel<<<4096, 256, 0, stream>>>(x, gamma1, beta1, h, flag, 1);
  // 256x128 tiles, 8 waves: 384 blocks (n-tiles 24 -> sxp 3)
  gemm_bt<0, 4, 2, false><<<384, 512, 0, stream>>>(h, WTq, 1024, 1024, 24, 3072,
                                                   nullptr, nullptr, nullptr,
                                                   Qb, Kb, Vtb, flag);
  // attn v14: v9 chassis, VALU-slimmed softmax
  attn_mfma<<<1024, 256, 0, stream>>>(Qb, Kb, Vtb, x, flag, x2);
  ln_kernel<<<4096, 256, 0, stream>>>(x2, gamma2, beta2, h2, flag, 0);
  // 256x128 tiles, 8 waves: 512 blocks (n-tiles 32 -> sxp 4)
  gemm_bt<1, 4, 2, false><<<512, 512, 0, stream>>>(h2, W1T, 1024, 1024, 32, 4096,
                                                   b1, nullptr, ff1,
                                                   nullptr, nullptr, nullptr, flag);
  // FFN2: 128x128 tiles, grid split-K2 -> 512 blocks (2/CU), bf16 partials
  gemm_bt<3, 2, 2, false><<<512, 256, 0, stream>>>(ff1, W2T, 2048, 4096, 8, 1024,
                                                   nullptr, nullptr, nullptr,
                                                   P0, P1, nullptr, flag);
  // reduce: out = P0 + P1 + b2 + x2
  ffn2_reduce<<<2048, 256, 0, stream>>>(P0, P1, b2, x2, d_out, flag);
}

// Round 11
// 318.598 us; speedup vs baseline: 1.0101x; 1.0101x over previous
//
#include <hip/hip_runtime.h>

typedef unsigned short u16;
typedef __bf16 bf16;
typedef __attribute__((ext_vector_type(8))) __bf16 bf16x8;
typedef __attribute__((ext_vector_type(4))) float f32x4;
typedef __attribute__((ext_vector_type(8))) unsigned short u16x8;
typedef unsigned long long u64;

__device__ __forceinline__ float bf2f(u16 h) {
  return __uint_as_float(((unsigned int)h) << 16);
}
__device__ __forceinline__ u16 f2bf(float f) {
  unsigned int u = __float_as_uint(f);
  return (u16)((u + 0x7fffu + ((u >> 16) & 1u)) >> 16);
}
__device__ __forceinline__ u16 ld_cv(const void* p, size_t i, int f32) {
  return f32 ? f2bf(((const float*)p)[i]) : ((const u16*)p)[i];
}
__device__ __forceinline__ float ld_f(const void* p, size_t i, int f32) {
  return f32 ? ((const float*)p)[i] : bf2f(((const u16*)p)[i]);
}
__device__ __forceinline__ void async16(const u16* g, u16* l) {
  __builtin_amdgcn_global_load_lds(
      (const __attribute__((address_space(1))) unsigned int*)g,
      (__attribute__((address_space(3))) unsigned int*)l, 16, 0, 0);
}
// raw v_exp_f32: D = 2^S0 (scale pre-folded into Q at the QKV epilogue)
__device__ __forceinline__ float exp2_raw(float x) {
  float r;
  asm("v_exp_f32 %0, %1" : "=v"(r) : "v"(x));
  return r;
}
// packed f32x2 -> bf16x2 (RNE); dst.lo = cvt(a), dst.hi = cvt(b)
__device__ __forceinline__ unsigned cvt_pk_bf16(float a, float b) {
  unsigned r;
  asm("v_cvt_pk_bf16_f32 %0, %1, %2" : "=v"(r) : "v"(a), "v"(b));
  return r;
}

// ---- mega-prep: weight transposes + fused dtype sniff --------------------
__global__ void prep_kernel(const u16* __restrict__ x,
                            const void* __restrict__ Wq, const void* __restrict__ Wk,
                            const void* __restrict__ Wv, const void* __restrict__ W1,
                            const void* __restrict__ W2,
                            u16* __restrict__ WTq, u16* __restrict__ W1T,
                            u16* __restrict__ W2T, int* __restrict__ flag) {
  __shared__ u16 tile[64][65];
  __shared__ int sm[4];
  const int tid = threadIdx.x;
  int me = 0;
#pragma unroll
  for (int j = 0; j < 4; j++) {
    const u16 v = x[(tid * 4 + j) * 2];
    const int e = (v >> 7) & 0xFF;
    me = me > e ? me : e;
  }
#pragma unroll
  for (int off = 32; off > 0; off >>= 1) {
    const int o = __shfl_down(me, off);
    me = me > o ? me : o;
  }
  if ((tid & 63) == 0) sm[tid >> 6] = me;
  __syncthreads();
  const int a01 = sm[0] > sm[1] ? sm[0] : sm[1];
  const int a23 = sm[2] > sm[3] ? sm[2] : sm[3];
  const int f = ((a01 > a23 ? a01 : a23) >= 140) ? 1 : 0;
  if (blockIdx.x == 0 && tid == 0) *flag = f;

  const int bid = blockIdx.x;
  const int lx = threadIdx.x & 63, ly = threadIdx.x >> 6;
  if (bid < 768) {
    const int bx = bid & 15, wh = bid >> 4;
    const int w = wh >> 4, hh = wh & 15;
    const int tr = bx * 64;
    const void* W = (w == 0) ? Wq : ((w == 1) ? Wk : Wv);
    const size_t hbase = (size_t)hh * 65536;
#pragma unroll
    for (int i = 0; i < 16; i++)
      tile[ly * 16 + i][lx] = ld_cv(W, hbase + (size_t)(tr + ly * 16 + i) * 64 + lx, f);
    __syncthreads();
#pragma unroll
    for (int i = 0; i < 16; i++)
      WTq[((size_t)(w * 1024 + hh * 64 + ly * 16 + i)) * 1024 + tr + lx] =
          tile[lx][ly * 16 + i];
  } else {
    const void* src;
    u16* dst;
    int R, C, tc, tr;
    if (bid < 1792) {
      const int j = bid - 768;
      src = W1; dst = W1T; R = 1024; C = 4096;
      tc = (j & 63) * 64; tr = (j >> 6) * 64;
    } else {
      const int j = bid - 1792;
      src = W2; dst = W2T; R = 4096; C = 1024;
      tc = (j & 15) * 64; tr = (j >> 4) * 64;
    }
#pragma unroll
    for (int i = 0; i < 16; i++)
      tile[ly * 16 + i][lx] = ld_cv(src, (size_t)(tr + ly * 16 + i) * C + tc + lx, f);
    __syncthreads();
#pragma unroll
    for (int i = 0; i < 16; i++)
      dst[(size_t)(tc + ly * 16 + i) * R + tr + lx] = tile[lx][ly * 16 + i];
  }
}

// ---------------- GEMM: C[m][n] = sum_k A[m][k] * BT[n][k] ----------------
// Chunk-XOR LDS swizzle (T2, rule #21). EPI==3: FFN2 split-K2 partials.
// EPI==0: Q output is pre-scaled by log2(e)/32 so attn uses raw v_exp_f32.
template <int EPI, int WR, int WC, bool MS>
__launch_bounds__(WR * WC * 64)
__global__ void gemm_bt(const u16* __restrict__ A, const u16* __restrict__ B,
                        int K, int KLD, int NX, int N,
                        const void* __restrict__ bias, const u16* __restrict__ res,
                        void* __restrict__ out,
                        u16* __restrict__ Qo, u16* __restrict__ Ko, u16* __restrict__ Vto,
                        const int* __restrict__ flag) {
  constexpr int BM = WR * 64, BN = WC * 64, T = WR * WC * 64;
  constexpr int RPA = T / 4;
  constexpr int RAH = BM / RPA;
  constexpr int RBH = BN / RPA;
  __shared__ __align__(16) u16 As[BM * 64];
  __shared__ __align__(16) u16 Bs[BN * 64];
  const int tid = threadIdx.x;
  const int bid = blockIdx.x;
  const int sxp = NX >> 3;
  const int xcd = bid & 7, j9 = bid >> 3;
  int m0, n0, koff = 0, khb = 0;
  if (EPI == 3) {
    m0 = (xcd * 4 + (j9 & 3)) * BM;
    n0 = ((j9 >> 2) & 7) * BN;
    khb = (j9 >> 5) & 1;
    koff = khb * K;
  } else if (MS) {
    m0 = (xcd * sxp + j9 % sxp) * BM;
    n0 = (j9 / sxp) * BN;
  } else {
    n0 = (xcd * sxp + j9 % sxp) * BN;
    m0 = (j9 / sxp) * BM;
  }
  const int wave = tid >> 6, lane = tid & 63;
  const int wm = (wave / WC) * 64, wn = (wave % WC) * 64;
  const int lm = lane & 15, lq = lane >> 4;
  const int fb = (EPI == 1 || EPI == 2) ? *flag : 0;

  const f32x4 zero = {0.f, 0.f, 0.f, 0.f};
  f32x4 acc[4][4];
#pragma unroll
  for (int i = 0; i < 4; i++)
#pragma unroll
    for (int j = 0; j < 4; j++) acc[i][j] = zero;

  const int ar = tid >> 2;
  const int ac = ((tid & 3) ^ ((tid >> 3) & 3)) * 8;
  const u16* Ag = A + (size_t)(m0 + ar) * KLD + koff + ac;
  const u16* Bg = B + (size_t)(n0 + ar) * KLD + koff + ac;
  u16* AsP = &As[tid * 8];
  u16* BsP = &Bs[tid * 8];
  const int rq = (lq ^ ((lm >> 1) & 3)) * 8;

  for (int k0 = 0; k0 < K; k0 += 64) {
#pragma unroll
    for (int hh = 0; hh < 2; hh++) {
#pragma unroll
      for (int c = 0; c < RAH; c++)
        async16(Ag + k0 + hh * 32 + (size_t)c * RPA * KLD,
                AsP + hh * BM * 32 + c * RPA * 32);
#pragma unroll
      for (int c = 0; c < RBH; c++)
        async16(Bg + k0 + hh * 32 + (size_t)c * RPA * KLD,
                BsP + hh * BN * 32 + c * RPA * 32);
    }
    __syncthreads();
    bf16x8 a0[4], a1[4], b0[4], b1[4];
#pragma unroll
    for (int i = 0; i < 4; i++) {
      a0[i] = *(const bf16x8*)&As[(wm + i * 16 + lm) * 32 + rq];
      a1[i] = *(const bf16x8*)&As[BM * 32 + (wm + i * 16 + lm) * 32 + rq];
    }
#pragma unroll
    for (int i = 0; i < 4; i++) {
      b0[i] = *(const bf16x8*)&Bs[(wn + i * 16 + lm) * 32 + rq];
      b1[i] = *(const bf16x8*)&Bs[BN * 32 + (wn + i * 16 + lm) * 32 + rq];
    }
#pragma unroll
    for (int i = 0; i < 4; i++)
#pragma unroll
      for (int j = 0; j < 4; j++) {
        acc[i][j] = __builtin_amdgcn_mfma_f32_16x16x32_bf16(a0[i], b0[j], acc[i][j], 0, 0, 0);
        acc[i][j] = __builtin_amdgcn_mfma_f32_16x16x32_bf16(a1[i], b1[j], acc[i][j], 0, 0, 0);
      }
    __syncthreads();
  }

  if (EPI == 0) {
#pragma unroll
    for (int i = 0; i < 4; i++) {
      const int row0 = m0 + wm + i * 16 + lq * 4;
      const int bb = row0 >> 11, t0 = row0 & 2047;
#pragma unroll
      for (int j = 0; j < 4; j++) {
        const int col = n0 + wn + j * 16 + lm;
        const int w = col >> 10, nn = col & 1023;
        const int hh = nn >> 6, e = nn & 63;
        if (w == 2) {
          ushort4 v4;
          v4.x = f2bf(acc[i][j][0]);
          v4.y = f2bf(acc[i][j][1]);
          v4.z = f2bf(acc[i][j][2]);
          v4.w = f2bf(acc[i][j][3]);
          *(ushort4*)&Vto[(((size_t)(bb * 16 + hh)) * 64 + e) * 2048 + t0] = v4;
        } else {
          u16* dst = (w == 0) ? Qo : Ko;
          const float qs = (w == 0) ? 0.04508422f : 1.0f;  // log2(e)/32 folded into Q
#pragma unroll
          for (int r = 0; r < 4; r++)
            dst[(((size_t)(bb * 16 + hh)) * 2048 + t0 + r) * 64 + e] =
                f2bf(acc[i][j][r] * qs);
        }
      }
    }
  } else if (EPI == 3) {
    u16* P = khb ? Ko : Qo;
#pragma unroll
    for (int i = 0; i < 4; i++) {
#pragma unroll
      for (int r = 0; r < 4; r++) {
        const int row = m0 + wm + i * 16 + lq * 4 + r;
#pragma unroll
        for (int j = 0; j < 4; j++) {
          const int col = n0 + wn + j * 16 + lm;
          P[(size_t)row * N + col] = f2bf(acc[i][j][r]);
        }
      }
    }
  } else {
#pragma unroll
    for (int i = 0; i < 4; i++) {
#pragma unroll
      for (int r = 0; r < 4; r++) {
        const int row = m0 + wm + i * 16 + lq * 4 + r;
#pragma unroll
        for (int j = 0; j < 4; j++) {
          const int col = n0 + wn + j * 16 + lm;
          const float c = acc[i][j][r];
          if (EPI == 1) {
            const float v = c + ld_f(bias, col, fb);
            ((u16*)out)[(size_t)row * N + col] = f2bf(v > 0.f ? v : 0.f);
          } else {
            const float v = c + ld_f(bias, col, fb) + bf2f(res[(size_t)row * N + col]);
            if (fb)
              ((float*)out)[(size_t)row * N + col] = v;
            else
              ((u16*)out)[(size_t)row * N + col] = f2bf(v);
          }
        }
      }
    }
  }
}

// ---------------- FFN2 split-K reduce: out = P0 + P1 + bias + res ----------
__launch_bounds__(256)
__global__ void ffn2_reduce(const u16* __restrict__ P0, const u16* __restrict__ P1,
                            const void* __restrict__ bias, const u16* __restrict__ res,
                            void* __restrict__ out, const int* __restrict__ flag) {
  const int f = *flag;
  const size_t i0 = ((size_t)blockIdx.x * 256 + threadIdx.x) * 8;
  const int col = (int)(i0 & 1023);
  const u16x8 a8 = *(const u16x8*)(P0 + i0);
  const u16x8 b8 = *(const u16x8*)(P1 + i0);
  const u16x8 r8 = *(const u16x8*)(res + i0);
  float v[8];
#pragma unroll
  for (int k = 0; k < 8; k++)
    v[k] = bf2f(a8[k]) + bf2f(b8[k]) + ld_f(bias, col + k, f) + bf2f(r8[k]);
  if (f) {
    float4 o0 = {v[0], v[1], v[2], v[3]};
    float4 o1 = {v[4], v[5], v[6], v[7]};
    *(float4*)((float*)out + i0) = o0;
    *(float4*)((float*)out + i0 + 4) = o1;
  } else {
    u16x8 o8;
#pragma unroll
    for (int k = 0; k < 8; k++) o8[k] = f2bf(v[k]);
    *(u16x8*)((u16*)out + i0) = o8;
  }
}

// ---------------- MFMA flash attention v15: split-phase pipelined ----------
// v14 chassis + single-buffer split-phase pipelining at FULL occupancy:
// within a tile, the K LDS region is dead after the QK MFMAs consume the K
// fragments, and V after the PV MFMAs. So stage K(t+1) right after QK(t)
// and V(t+1) right after PV(t) -- same 8KB/wave buffer, 16 waves/CU kept,
// each DMA gets ~300cy compute cover; the per-tile vmcnt(0) drain becomes
// two counted vmcnt(4) waits. sched_barrier(0) pins DMA issue after the
// MFMAs (whose lgkm waits prove the ds_reads of the old data completed).
// kk/vf reads hoisted out of the s-loop (s-invariant; halves LDS reads).
__launch_bounds__(256)
__global__ void attn_mfma(const u16* __restrict__ Q, const u16* __restrict__ K,
                          const u16* __restrict__ Vt, const void* __restrict__ xres,
                          const int* __restrict__ flag, u16* __restrict__ x2) {
  __shared__ __align__(16) unsigned char smem[35328];
  const int tid = threadIdx.x;
  const int wave = tid >> 6, lane = tid & 63;
  const int lm = lane & 15, quad = lane >> 4;
  const int bid = blockIdx.x;
  const int xcd = bid & 7, jj = bid >> 3;
  const int bh = xcd + 8 * (jj & 3);
  const int pair = jj >> 2;  // 0..31
  const int b = bh >> 4, h = bh & 15;
  const int f32in = *flag;

  u16* stw = (u16*)smem + wave * 4096;  // 8KB per wave
  u16* Ksw = stw;                        // [half][32 rows][4 chunks x 8]
  u16* Vsw = stw + 2048;                 // [64 rows][4 chunks x 8]
  float (*Olds)[32][68] = (float(*)[32][68])smem;          // 34816 B
  float (*Llds)[2][16] = (float(*)[2][16])(smem + 34816);  // 512 B

  const u16* Kbh = K + (size_t)bh * 131072;
  const u16* Vbh = Vt + (size_t)bh * 131072;
  const f32x4 zero = {0.f, 0.f, 0.f, 0.f};
  const int srow = lane >> 2;
  const int sch2 = (((lane & 3) ^ ((srow >> 1) & 3))) * 8;
  const int rk = (lm >> 1) & 3;

  union V8 { bf16x8 v; struct { u64 lo, hi; } q; };
  u16x8 ob;
#pragma unroll
  for (int k = 0; k < 8; k++) ob[k] = 0x3F80;
  const bf16x8 ones = *(const bf16x8*)&ob;

  auto stageK = [&](int t) {
    const int ks = t * 32;
#pragma unroll
    for (int hh2 = 0; hh2 < 2; hh2++)
#pragma unroll
      for (int c = 0; c < 2; c++)
        async16(Kbh + (size_t)(ks + c * 16 + srow) * 64 + hh2 * 32 + sch2,
                Ksw + hh2 * 1024 + c * 512 + lane * 8);
  };
  auto stageV = [&](int t) {
    const int ks = t * 32;
#pragma unroll
    for (int c = 0; c < 4; c++)
      async16(Vbh + (size_t)(c * 16 + srow) * 2048 + ks + sch2,
              Vsw + c * 512 + lane * 8);
  };

#pragma unroll 1
  for (int phase = 0; phase < 2; phase++) {
    const int qb = phase ? (63 - pair) : pair;
    const int qw0 = qb * 32;

    bf16x8 qf[2][2];
#pragma unroll
    for (int s = 0; s < 2; s++) {
      const u16* Qp = Q + ((size_t)bh * 2048 + qw0 + s * 16 + lm) * 64 + quad * 8;
      qf[s][0] = *(const bf16x8*)Qp;
      qf[s][1] = *(const bf16x8*)(Qp + 32);
    }
    __builtin_amdgcn_s_waitcnt(0x0F70);  // qf resident; vm queue empty
    f32x4 ot[2][4];
    f32x4 al[2];
#pragma unroll
    for (int s = 0; s < 2; s++) {
#pragma unroll
      for (int j = 0; j < 4; j++) ot[s][j] = zero;
      al[s] = zero;
    }

    const int nt = qb + 1;
    const int si = (nt * wave) >> 2;
    const int ei = (nt * (wave + 1)) >> 2;

    if (si < ei) { stageK(si); stageV(si); }  // 4 + 4 in flight (K older)

#pragma unroll 1
    for (int t = si; t < ei; t++) {
      asm volatile("s_waitcnt vmcnt(4)" ::: "memory");  // K(t) landed
      // hoisted K fragments (s-invariant)
      bf16x8 kk[2][2];
#pragma unroll
      for (int hh = 0; hh < 2; hh++) {
        kk[hh][0] = *(const bf16x8*)&Ksw[(hh * 16 + lm) * 32 + (quad ^ rk) * 8];
        kk[hh][1] = *(const bf16x8*)&Ksw[1024 + (hh * 16 + lm) * 32 + (quad ^ rk) * 8];
      }
      f32x4 S[2][2];
#pragma unroll
      for (int s = 0; s < 2; s++)
#pragma unroll
        for (int hh = 0; hh < 2; hh++) {
          f32x4 a = zero;
          a = __builtin_amdgcn_mfma_f32_16x16x32_bf16(kk[hh][0], qf[s][0], a, 0, 0, 0);
          a = __builtin_amdgcn_mfma_f32_16x16x32_bf16(kk[hh][1], qf[s][1], a, 0, 0, 0);
          S[s][hh] = a;
        }
      __builtin_amdgcn_sched_barrier(0);  // pin: QK (and its lgkm) before K-restage
      const bool more = (t + 1 < ei);
      if (more) {
        stageK(t + 1);                                    // K region dead now
        asm volatile("s_waitcnt vmcnt(4)" ::: "memory");  // V(t) landed
      } else {
        asm volatile("s_waitcnt vmcnt(0)" ::: "memory");
      }
      // hoisted V fragments (s-invariant)
      V8 vf[4];
#pragma unroll
      for (int j = 0; j < 4; j++) {
        vf[j].q.lo = *(const u64*)&Vsw[(j * 16 + lm) * 32 +
                                       (((quad >> 1)) ^ rk) * 8 + (quad & 1) * 4];
        vf[j].q.hi = *(const u64*)&Vsw[(j * 16 + lm) * 32 +
                                       (((quad >> 1) | 2) ^ rk) * 8 + (quad & 1) * 4];
      }
      const bool maskT = (t == qb);
#pragma unroll
      for (int s = 0; s < 2; s++) {
        float p[2][4];
#pragma unroll
        for (int hh = 0; hh < 2; hh++)
#pragma unroll
          for (int r = 0; r < 4; r++)
            p[hh][r] = exp2_raw(S[s][hh][r]);  // scale pre-folded into Q
        if (maskT) {
#pragma unroll
          for (int hh = 0; hh < 2; hh++)
#pragma unroll
            for (int r = 0; r < 4; r++)
              if (hh * 16 + quad * 4 + r > s * 16 + lm) p[hh][r] = 0.f;
        }
        unsigned pk[4];
        pk[0] = cvt_pk_bf16(p[0][0], p[0][1]);
        pk[1] = cvt_pk_bf16(p[0][2], p[0][3]);
        pk[2] = cvt_pk_bf16(p[1][0], p[1][1]);
        pk[3] = cvt_pk_bf16(p[1][2], p[1][3]);
        const bf16x8 pf = *(const bf16x8*)pk;
        al[s] = __builtin_amdgcn_mfma_f32_16x16x32_bf16(ones, pf, al[s], 0, 0, 0);
#pragma unroll
        for (int j = 0; j < 4; j++)
          ot[s][j] = __builtin_amdgcn_mfma_f32_16x16x32_bf16(vf[j].v, pf, ot[s][j], 0, 0, 0);
      }
      __builtin_amdgcn_sched_barrier(0);  // pin: PV (and its lgkm) before V-restage
      if (more) stageV(t + 1);            // V region dead now
    }

    __syncthreads();  // ALL waves done staging/reading before Olds overwrite

#pragma unroll
    for (int s = 0; s < 2; s++)
#pragma unroll
      for (int j = 0; j < 4; j++)
        *(f32x4*)&Olds[wave][s * 16 + lm][j * 16 + quad * 4] = ot[s][j];
    if (quad == 0) {
      Llds[wave][0][lm] = al[0][0];  // full k-range sum via ones-MFMA
      Llds[wave][1][lm] = al[1][0];
    }
    __syncthreads();
    const int q = tid >> 3;
    const int e0 = (tid & 7) * 8;
    f32x4 oa = zero, obv = zero;
#pragma unroll
    for (int w = 0; w < 4; w++) {
      oa += *(const f32x4*)&Olds[w][q][e0];
      obv += *(const f32x4*)&Olds[w][q][e0 + 4];
    }
    const float lt = Llds[0][q >> 4][q & 15] + Llds[1][q >> 4][q & 15] +
                     Llds[2][q >> 4][q & 15] + Llds[3][q >> 4][q & 15];
    const float linv = 1.f / lt;
    const size_t rowbase = ((size_t)(b * 2048 + qw0 + q)) * 1024 + h * 64 + e0;
    float xv[8];
    if (f32in) {
      const float* xf = (const float*)xres + rowbase;
      const float4 u0 = *(const float4*)xf;
      const float4 u1 = *(const float4*)(xf + 4);
      xv[0] = u0.x; xv[1] = u0.y; xv[2] = u0.z; xv[3] = u0.w;
      xv[4] = u1.x; xv[5] = u1.y; xv[6] = u1.z; xv[7] = u1.w;
    } else {
      const u16x8 u = *(const u16x8*)((const u16*)xres + rowbase);
#pragma unroll
      for (int k = 0; k < 8; k++) xv[k] = bf2f(u[k]);
    }
    u16x8 o8;
#pragma unroll
    for (int k = 0; k < 4; k++) o8[k] = f2bf(xv[k] + oa[k] * linv);
#pragma unroll
    for (int k = 0; k < 4; k++) o8[4 + k] = f2bf(xv[4 + k] + obv[k] * linv);
    *(u16x8*)&x2[rowbase] = o8;
    __syncthreads();
  }
}

// ---------------- LayerNorm (ddof=1, eps=1e-5), raw dual-dtype inputs ------
__launch_bounds__(256)
__global__ void ln_kernel(const void* __restrict__ x, const void* __restrict__ gamma,
                          const void* __restrict__ beta, u16* __restrict__ out,
                          const int* __restrict__ flag, int xraw) {
  const size_t row = blockIdx.x;
  const int tid = threadIdx.x;
  const int f = *flag;
  const int fx = xraw ? f : 0;
  float v0, v1, v2, v3;
  if (fx) {
    const float4 v = *((const float4*)x + row * 256 + tid);
    v0 = v.x; v1 = v.y; v2 = v.z; v3 = v.w;
  } else {
    const ushort4 u = *((const ushort4*)x + row * 256 + tid);
    v0 = bf2f(u.x); v1 = bf2f(u.y); v2 = bf2f(u.z); v3 = bf2f(u.w);
  }
  float s = v0 + v1 + v2 + v3;
  float sq = v0 * v0 + v1 * v1 + v2 * v2 + v3 * v3;
#pragma unroll
  for (int off = 32; off > 0; off >>= 1) {
    s += __shfl_down(s, off);
    sq += __shfl_down(sq, off);
  }
  __shared__ float ss[4], ssq[4];
  if ((tid & 63) == 0) { ss[tid >> 6] = s; ssq[tid >> 6] = sq; }
  __syncthreads();
  s = ss[0] + ss[1] + ss[2] + ss[3];
  sq = ssq[0] + ssq[1] + ssq[2] + ssq[3];
  const float mean = s * (1.f / 1024.f);
  const float var = (sq - 1024.f * mean * mean) * (1.f / 1023.f);
  const float rs = rsqrtf(var + 1e-5f);
  const int c0 = tid * 4;
  ushort4 o;
  o.x = f2bf(ld_f(gamma, c0 + 0, f) * (v0 - mean) * rs + ld_f(beta, c0 + 0, f));
  o.y = f2bf(ld_f(gamma, c0 + 1, f) * (v1 - mean) * rs + ld_f(beta, c0 + 1, f));
  o.z = f2bf(ld_f(gamma, c0 + 2, f) * (v2 - mean) * rs + ld_f(beta, c0 + 2, f));
  o.w = f2bf(ld_f(gamma, c0 + 3, f) * (v3 - mean) * rs + ld_f(beta, c0 + 3, f));
  *(ushort4*)&out[row * 1024 + tid * 4] = o;
}

extern "C" void kernel_launch(void* const* d_in, const int* in_sizes, int n_in,
                              void* d_out, int out_size, void* d_ws, size_t ws_size,
                              hipStream_t stream) {
  const void* x      = d_in[0];
  const void* Wq     = d_in[1];
  const void* Wk     = d_in[2];
  const void* Wv     = d_in[3];
  const void* W1     = d_in[4];
  const void* b1     = d_in[5];
  const void* W2     = d_in[6];
  const void* b2     = d_in[7];
  const void* gamma1 = d_in[8];
  const void* beta1  = d_in[9];
  const void* gamma2 = d_in[10];
  const void* beta2  = d_in[11];
  u16* ws = (u16*)d_ws;

  const size_t M4 = 4194304;
  u16* h   = ws;            // slot 0 (later: ff1 spans 0-3)
  u16* Qb  = ws + 1 * M4;   // slot 1
  u16* Kb  = ws + 2 * M4;   // slot 2
  u16* Vtb = ws + 3 * M4;   // slot 3
  u16* WTq = ws + 4 * M4;   // slot 4 (later: x2)
  u16* x2  = ws + 4 * M4;
  u16* h2  = ws + 5 * M4;   // slot 5 (later: FFN2 partial P0)
  u16* W1T = ws + 6 * M4;   // slot 6 (later: FFN2 partial P1)
  u16* W2T = ws + 7 * M4;   // slot 7
  u16* ff1 = ws;            // slots 0-3
  u16* P0  = ws + 5 * M4;   // bf16 partial kq=0 (h2 dead after FFN1)
  u16* P1  = ws + 6 * M4;   // bf16 partial kq=1 (W1T dead after FFN1)
  int* flag = (int*)(ws + 8 * M4 + 9216);

  // prep (with fused dtype sniff; block 0 publishes *flag)
  prep_kernel<<<2816, 256, 0, stream>>>((const u16*)x, Wq, Wk, Wv, W1, W2,
                                        WTq, W1T, W2T, flag);
  ln_kernel<<<4096, 256, 0, stream>>>(x, gamma1, beta1, h, flag, 1);
  // 256x128 tiles, 8 waves: 384 blocks (n-tiles 24 -> sxp 3)
  gemm_bt<0, 4, 2, false><<<384, 512, 0, stream>>>(h, WTq, 1024, 1024, 24, 3072,
                                                   nullptr, nullptr, nullptr,
                                                   Qb, Kb, Vtb, flag);
  // attn v15: split-phase single-buffer pipelining, 16 waves/CU
  attn_mfma<<<1024, 256, 0, stream>>>(Qb, Kb, Vtb, x, flag, x2);
  ln_kernel<<<4096, 256, 0, stream>>>(x2, gamma2, beta2, h2, flag, 0);
  // 256x128 tiles, 8 waves: 512 blocks (n-tiles 32 -> sxp 4)
  gemm_bt<1, 4, 2, false><<<512, 512, 0, stream>>>(h2, W1T, 1024, 1024, 32, 4096,
                                                   b1, nullptr, ff1,
                                                   nullptr, nullptr, nullptr, flag);
  // FFN2: 128x128 tiles, grid split-K2 -> 512 blocks (2/CU), bf16 partials
  gemm_bt<3, 2, 2, false><<<512, 256, 0, stream>>>(ff1, W2T, 2048, 4096, 8, 1024,
                                                   nullptr, nullptr, nullptr,
                                                   P0, P1, nullptr, flag);
  // reduce: out = P0 + P1 + b2 + x2
  ffn2_reduce<<<2048, 256, 0, stream>>>(P0, P1, b2, x2, d_out, flag);
}

// Round 12
// 316.925 us; speedup vs baseline: 1.0154x; 1.0053x over previous
//
#include <hip/hip_runtime.h>

typedef unsigned short u16;
typedef __bf16 bf16;
typedef __attribute__((ext_vector_type(8))) __bf16 bf16x8;
typedef __attribute__((ext_vector_type(4))) float f32x4;
typedef __attribute__((ext_vector_type(8))) unsigned short u16x8;
typedef unsigned long long u64;

__device__ __forceinline__ float bf2f(u16 h) {
  return __uint_as_float(((unsigned int)h) << 16);
}
__device__ __forceinline__ u16 f2bf(float f) {
  unsigned int u = __float_as_uint(f);
  return (u16)((u + 0x7fffu + ((u >> 16) & 1u)) >> 16);
}
__device__ __forceinline__ u16 ld_cv(const void* p, size_t i, int f32) {
  return f32 ? f2bf(((const float*)p)[i]) : ((const u16*)p)[i];
}
__device__ __forceinline__ float ld_f(const void* p, size_t i, int f32) {
  return f32 ? ((const float*)p)[i] : bf2f(((const u16*)p)[i]);
}
__device__ __forceinline__ void async16(const u16* g, u16* l) {
  __builtin_amdgcn_global_load_lds(
      (const __attribute__((address_space(1))) unsigned int*)g,
      (__attribute__((address_space(3))) unsigned int*)l, 16, 0, 0);
}
// raw v_exp_f32: D = 2^S0 (scale pre-folded into Q at the QKV epilogue)
__device__ __forceinline__ float exp2_raw(float x) {
  float r;
  asm("v_exp_f32 %0, %1" : "=v"(r) : "v"(x));
  return r;
}
// packed f32x2 -> bf16x2 (RNE); dst.lo = cvt(a), dst.hi = cvt(b)
__device__ __forceinline__ unsigned cvt_pk_bf16(float a, float b) {
  unsigned r;
  asm("v_cvt_pk_bf16_f32 %0, %1, %2" : "=v"(r) : "v"(a), "v"(b));
  return r;
}

// ---- mega-prep: weight transposes + fused dtype sniff + fused ln1 --------
// Blocks 0..2815: weight transposes. Blocks 2816..6911: LayerNorm1 on row
// (bid-2816). Every block computes the dtype flag locally (2KB L2-hot read);
// block 0 publishes it for downstream kernels. ln1 is BW-bound and
// independent of the transposes, so it overlaps under prep's BW phase --
// one fewer serializing launch.
__global__ void prep_kernel(const u16* __restrict__ x,
                            const void* __restrict__ Wq, const void* __restrict__ Wk,
                            const void* __restrict__ Wv, const void* __restrict__ W1,
                            const void* __restrict__ W2,
                            u16* __restrict__ WTq, u16* __restrict__ W1T,
                            u16* __restrict__ W2T,
                            const void* __restrict__ gamma1,
                            const void* __restrict__ beta1,
                            u16* __restrict__ hOut, int* __restrict__ flag) {
  __shared__ u16 tile[64][65];
  __shared__ int sm[4];
  __shared__ float ss[4], ssq[4];
  const int tid = threadIdx.x;
  int me = 0;
#pragma unroll
  for (int j = 0; j < 4; j++) {
    const u16 v = x[(tid * 4 + j) * 2];
    const int e = (v >> 7) & 0xFF;
    me = me > e ? me : e;
  }
#pragma unroll
  for (int off = 32; off > 0; off >>= 1) {
    const int o = __shfl_down(me, off);
    me = me > o ? me : o;
  }
  if ((tid & 63) == 0) sm[tid >> 6] = me;
  __syncthreads();
  const int a01 = sm[0] > sm[1] ? sm[0] : sm[1];
  const int a23 = sm[2] > sm[3] ? sm[2] : sm[3];
  const int f = ((a01 > a23 ? a01 : a23) >= 140) ? 1 : 0;
  if (blockIdx.x == 0 && tid == 0) *flag = f;

  const int bid = blockIdx.x;
  if (bid >= 2816) {
    // ---- fused LayerNorm1 (xraw=1: x dtype follows f) ----
    const size_t row = bid - 2816;
    float v0, v1, v2, v3;
    if (f) {
      const float4 v = *((const float4*)x + row * 256 + tid);
      v0 = v.x; v1 = v.y; v2 = v.z; v3 = v.w;
    } else {
      const ushort4 u = *((const ushort4*)x + row * 256 + tid);
      v0 = bf2f(u.x); v1 = bf2f(u.y); v2 = bf2f(u.z); v3 = bf2f(u.w);
    }
    float s = v0 + v1 + v2 + v3;
    float sq = v0 * v0 + v1 * v1 + v2 * v2 + v3 * v3;
#pragma unroll
    for (int off = 32; off > 0; off >>= 1) {
      s += __shfl_down(s, off);
      sq += __shfl_down(sq, off);
    }
    if ((tid & 63) == 0) { ss[tid >> 6] = s; ssq[tid >> 6] = sq; }
    __syncthreads();
    s = ss[0] + ss[1] + ss[2] + ss[3];
    sq = ssq[0] + ssq[1] + ssq[2] + ssq[3];
    const float mean = s * (1.f / 1024.f);
    const float var = (sq - 1024.f * mean * mean) * (1.f / 1023.f);
    const float rs = rsqrtf(var + 1e-5f);
    const int c0 = tid * 4;
    ushort4 o;
    o.x = f2bf(ld_f(gamma1, c0 + 0, f) * (v0 - mean) * rs + ld_f(beta1, c0 + 0, f));
    o.y = f2bf(ld_f(gamma1, c0 + 1, f) * (v1 - mean) * rs + ld_f(beta1, c0 + 1, f));
    o.z = f2bf(ld_f(gamma1, c0 + 2, f) * (v2 - mean) * rs + ld_f(beta1, c0 + 2, f));
    o.w = f2bf(ld_f(gamma1, c0 + 3, f) * (v3 - mean) * rs + ld_f(beta1, c0 + 3, f));
    *(ushort4*)&hOut[row * 1024 + tid * 4] = o;
    return;
  }

  const int lx = threadIdx.x & 63, ly = threadIdx.x >> 6;
  if (bid < 768) {
    const int bx = bid & 15, wh = bid >> 4;
    const int w = wh >> 4, hh = wh & 15;
    const int tr = bx * 64;
    const void* W = (w == 0) ? Wq : ((w == 1) ? Wk : Wv);
    const size_t hbase = (size_t)hh * 65536;
#pragma unroll
    for (int i = 0; i < 16; i++)
      tile[ly * 16 + i][lx] = ld_cv(W, hbase + (size_t)(tr + ly * 16 + i) * 64 + lx, f);
    __syncthreads();
#pragma unroll
    for (int i = 0; i < 16; i++)
      WTq[((size_t)(w * 1024 + hh * 64 + ly * 16 + i)) * 1024 + tr + lx] =
          tile[lx][ly * 16 + i];
  } else {
    const void* src;
    u16* dst;
    int R, C, tc, tr;
    if (bid < 1792) {
      const int j = bid - 768;
      src = W1; dst = W1T; R = 1024; C = 4096;
      tc = (j & 63) * 64; tr = (j >> 6) * 64;
    } else {
      const int j = bid - 1792;
      src = W2; dst = W2T; R = 4096; C = 1024;
      tc = (j & 15) * 64; tr = (j >> 4) * 64;
    }
#pragma unroll
    for (int i = 0; i < 16; i++)
      tile[ly * 16 + i][lx] = ld_cv(src, (size_t)(tr + ly * 16 + i) * C + tc + lx, f);
    __syncthreads();
#pragma unroll
    for (int i = 0; i < 16; i++)
      dst[(size_t)(tc + ly * 16 + i) * R + tr + lx] = tile[lx][ly * 16 + i];
  }
}

// ---------------- GEMM: C[m][n] = sum_k A[m][k] * BT[n][k] ----------------
// Chunk-XOR LDS swizzle (T2, rule #21). EPI==3: FFN2 split-K2 partials.
// EPI==0: Q output is pre-scaled by log2(e)/32 so attn uses raw v_exp_f32.
template <int EPI, int WR, int WC, bool MS>
__launch_bounds__(WR * WC * 64)
__global__ void gemm_bt(const u16* __restrict__ A, const u16* __restrict__ B,
                        int K, int KLD, int NX, int N,
                        const void* __restrict__ bias, const u16* __restrict__ res,
                        void* __restrict__ out,
                        u16* __restrict__ Qo, u16* __restrict__ Ko, u16* __restrict__ Vto,
                        const int* __restrict__ flag) {
  constexpr int BM = WR * 64, BN = WC * 64, T = WR * WC * 64;
  constexpr int RPA = T / 4;
  constexpr int RAH = BM / RPA;
  constexpr int RBH = BN / RPA;
  __shared__ __align__(16) u16 As[BM * 64];
  __shared__ __align__(16) u16 Bs[BN * 64];
  const int tid = threadIdx.x;
  const int bid = blockIdx.x;
  const int sxp = NX >> 3;
  const int xcd = bid & 7, j9 = bid >> 3;
  int m0, n0, koff = 0, khb = 0;
  if (EPI == 3) {
    m0 = (xcd * 4 + (j9 & 3)) * BM;
    n0 = ((j9 >> 2) & 7) * BN;
    khb = (j9 >> 5) & 1;
    koff = khb * K;
  } else if (MS) {
    m0 = (xcd * sxp + j9 % sxp) * BM;
    n0 = (j9 / sxp) * BN;
  } else {
    n0 = (xcd * sxp + j9 % sxp) * BN;
    m0 = (j9 / sxp) * BM;
  }
  const int wave = tid >> 6, lane = tid & 63;
  const int wm = (wave / WC) * 64, wn = (wave % WC) * 64;
  const int lm = lane & 15, lq = lane >> 4;
  const int fb = (EPI == 1 || EPI == 2) ? *flag : 0;

  const f32x4 zero = {0.f, 0.f, 0.f, 0.f};
  f32x4 acc[4][4];
#pragma unroll
  for (int i = 0; i < 4; i++)
#pragma unroll
    for (int j = 0; j < 4; j++) acc[i][j] = zero;

  const int ar = tid >> 2;
  const int ac = ((tid & 3) ^ ((tid >> 3) & 3)) * 8;
  const u16* Ag = A + (size_t)(m0 + ar) * KLD + koff + ac;
  const u16* Bg = B + (size_t)(n0 + ar) * KLD + koff + ac;
  u16* AsP = &As[tid * 8];
  u16* BsP = &Bs[tid * 8];
  const int rq = (lq ^ ((lm >> 1) & 3)) * 8;

  for (int k0 = 0; k0 < K; k0 += 64) {
#pragma unroll
    for (int hh = 0; hh < 2; hh++) {
#pragma unroll
      for (int c = 0; c < RAH; c++)
        async16(Ag + k0 + hh * 32 + (size_t)c * RPA * KLD,
                AsP + hh * BM * 32 + c * RPA * 32);
#pragma unroll
      for (int c = 0; c < RBH; c++)
        async16(Bg + k0 + hh * 32 + (size_t)c * RPA * KLD,
                BsP + hh * BN * 32 + c * RPA * 32);
    }
    __syncthreads();
    bf16x8 a0[4], a1[4], b0[4], b1[4];
#pragma unroll
    for (int i = 0; i < 4; i++) {
      a0[i] = *(const bf16x8*)&As[(wm + i * 16 + lm) * 32 + rq];
      a1[i] = *(const bf16x8*)&As[BM * 32 + (wm + i * 16 + lm) * 32 + rq];
    }
#pragma unroll
    for (int i = 0; i < 4; i++) {
      b0[i] = *(const bf16x8*)&Bs[(wn + i * 16 + lm) * 32 + rq];
      b1[i] = *(const bf16x8*)&Bs[BN * 32 + (wn + i * 16 + lm) * 32 + rq];
    }
#pragma unroll
    for (int i = 0; i < 4; i++)
#pragma unroll
      for (int j = 0; j < 4; j++) {
        acc[i][j] = __builtin_amdgcn_mfma_f32_16x16x32_bf16(a0[i], b0[j], acc[i][j], 0, 0, 0);
        acc[i][j] = __builtin_amdgcn_mfma_f32_16x16x32_bf16(a1[i], b1[j], acc[i][j], 0, 0, 0);
      }
    __syncthreads();
  }

  if (EPI == 0) {
#pragma unroll
    for (int i = 0; i < 4; i++) {
      const int row0 = m0 + wm + i * 16 + lq * 4;
      const int bb = row0 >> 11, t0 = row0 & 2047;
#pragma unroll
      for (int j = 0; j < 4; j++) {
        const int col = n0 + wn + j * 16 + lm;
        const int w = col >> 10, nn = col & 1023;
        const int hh = nn >> 6, e = nn & 63;
        if (w == 2) {
          ushort4 v4;
          v4.x = f2bf(acc[i][j][0]);
          v4.y = f2bf(acc[i][j][1]);
          v4.z = f2bf(acc[i][j][2]);
          v4.w = f2bf(acc[i][j][3]);
          *(ushort4*)&Vto[(((size_t)(bb * 16 + hh)) * 64 + e) * 2048 + t0] = v4;
        } else {
          u16* dst = (w == 0) ? Qo : Ko;
          const float qs = (w == 0) ? 0.04508422f : 1.0f;  // log2(e)/32 folded into Q
#pragma unroll
          for (int r = 0; r < 4; r++)
            dst[(((size_t)(bb * 16 + hh)) * 2048 + t0 + r) * 64 + e] =
                f2bf(acc[i][j][r] * qs);
        }
      }
    }
  } else if (EPI == 3) {
    u16* P = khb ? Ko : Qo;
#pragma unroll
    for (int i = 0; i < 4; i++) {
#pragma unroll
      for (int r = 0; r < 4; r++) {
        const int row = m0 + wm + i * 16 + lq * 4 + r;
#pragma unroll
        for (int j = 0; j < 4; j++) {
          const int col = n0 + wn + j * 16 + lm;
          P[(size_t)row * N + col] = f2bf(acc[i][j][r]);
        }
      }
    }
  } else {
#pragma unroll
    for (int i = 0; i < 4; i++) {
#pragma unroll
      for (int r = 0; r < 4; r++) {
        const int row = m0 + wm + i * 16 + lq * 4 + r;
#pragma unroll
        for (int j = 0; j < 4; j++) {
          const int col = n0 + wn + j * 16 + lm;
          const float c = acc[i][j][r];
          if (EPI == 1) {
            const float v = c + ld_f(bias, col, fb);
            ((u16*)out)[(size_t)row * N + col] = f2bf(v > 0.f ? v : 0.f);
          } else {
            const float v = c + ld_f(bias, col, fb) + bf2f(res[(size_t)row * N + col]);
            if (fb)
              ((float*)out)[(size_t)row * N + col] = v;
            else
              ((u16*)out)[(size_t)row * N + col] = f2bf(v);
          }
        }
      }
    }
  }
}

// ---------------- FFN2 split-K reduce: out = P0 + P1 + bias + res ----------
__launch_bounds__(256)
__global__ void ffn2_reduce(const u16* __restrict__ P0, const u16* __restrict__ P1,
                            const void* __restrict__ bias, const u16* __restrict__ res,
                            void* __restrict__ out, const int* __restrict__ flag) {
  const int f = *flag;
  const size_t i0 = ((size_t)blockIdx.x * 256 + threadIdx.x) * 8;
  const int col = (int)(i0 & 1023);
  const u16x8 a8 = *(const u16x8*)(P0 + i0);
  const u16x8 b8 = *(const u16x8*)(P1 + i0);
  const u16x8 r8 = *(const u16x8*)(res + i0);
  float v[8];
#pragma unroll
  for (int k = 0; k < 8; k++)
    v[k] = bf2f(a8[k]) + bf2f(b8[k]) + ld_f(bias, col + k, f) + bf2f(r8[k]);
  if (f) {
    float4 o0 = {v[0], v[1], v[2], v[3]};
    float4 o1 = {v[4], v[5], v[6], v[7]};
    *(float4*)((float*)out + i0) = o0;
    *(float4*)((float*)out + i0 + 4) = o1;
  } else {
    u16x8 o8;
#pragma unroll
    for (int k = 0; k < 8; k++) o8[k] = f2bf(v[k]);
    *(u16x8*)((u16*)out + i0) = o8;
  }
}

// ---------------- MFMA flash attention v15: split-phase pipelined ----------
// (measured ~50.5us, equivalent to v14 within noise; kept as current best)
__launch_bounds__(256)
__global__ void attn_mfma(const u16* __restrict__ Q, const u16* __restrict__ K,
                          const u16* __restrict__ Vt, const void* __restrict__ xres,
                          const int* __restrict__ flag, u16* __restrict__ x2) {
  __shared__ __align__(16) unsigned char smem[35328];
  const int tid = threadIdx.x;
  const int wave = tid >> 6, lane = tid & 63;
  const int lm = lane & 15, quad = lane >> 4;
  const int bid = blockIdx.x;
  const int xcd = bid & 7, jj = bid >> 3;
  const int bh = xcd + 8 * (jj & 3);
  const int pair = jj >> 2;  // 0..31
  const int b = bh >> 4, h = bh & 15;
  const int f32in = *flag;

  u16* stw = (u16*)smem + wave * 4096;  // 8KB per wave
  u16* Ksw = stw;                        // [half][32 rows][4 chunks x 8]
  u16* Vsw = stw + 2048;                 // [64 rows][4 chunks x 8]
  float (*Olds)[32][68] = (float(*)[32][68])smem;          // 34816 B
  float (*Llds)[2][16] = (float(*)[2][16])(smem + 34816);  // 512 B

  const u16* Kbh = K + (size_t)bh * 131072;
  const u16* Vbh = Vt + (size_t)bh * 131072;
  const f32x4 zero = {0.f, 0.f, 0.f, 0.f};
  const int srow = lane >> 2;
  const int sch2 = (((lane & 3) ^ ((srow >> 1) & 3))) * 8;
  const int rk = (lm >> 1) & 3;

  union V8 { bf16x8 v; struct { u64 lo, hi; } q; };
  u16x8 ob;
#pragma unroll
  for (int k = 0; k < 8; k++) ob[k] = 0x3F80;
  const bf16x8 ones = *(const bf16x8*)&ob;

  auto stageK = [&](int t) {
    const int ks = t * 32;
#pragma unroll
    for (int hh2 = 0; hh2 < 2; hh2++)
#pragma unroll
      for (int c = 0; c < 2; c++)
        async16(Kbh + (size_t)(ks + c * 16 + srow) * 64 + hh2 * 32 + sch2,
                Ksw + hh2 * 1024 + c * 512 + lane * 8);
  };
  auto stageV = [&](int t) {
    const int ks = t * 32;
#pragma unroll
    for (int c = 0; c < 4; c++)
      async16(Vbh + (size_t)(c * 16 + srow) * 2048 + ks + sch2,
              Vsw + c * 512 + lane * 8);
  };

#pragma unroll 1
  for (int phase = 0; phase < 2; phase++) {
    const int qb = phase ? (63 - pair) : pair;
    const int qw0 = qb * 32;

    bf16x8 qf[2][2];
#pragma unroll
    for (int s = 0; s < 2; s++) {
      const u16* Qp = Q + ((size_t)bh * 2048 + qw0 + s * 16 + lm) * 64 + quad * 8;
      qf[s][0] = *(const bf16x8*)Qp;
      qf[s][1] = *(const bf16x8*)(Qp + 32);
    }
    __builtin_amdgcn_s_waitcnt(0x0F70);  // qf resident; vm queue empty
    f32x4 ot[2][4];
    f32x4 al[2];
#pragma unroll
    for (int s = 0; s < 2; s++) {
#pragma unroll
      for (int j = 0; j < 4; j++) ot[s][j] = zero;
      al[s] = zero;
    }

    const int nt = qb + 1;
    const int si = (nt * wave) >> 2;
    const int ei = (nt * (wave + 1)) >> 2;

    if (si < ei) { stageK(si); stageV(si); }  // 4 + 4 in flight (K older)

#pragma unroll 1
    for (int t = si; t < ei; t++) {
      asm volatile("s_waitcnt vmcnt(4)" ::: "memory");  // K(t) landed
      bf16x8 kk[2][2];
#pragma unroll
      for (int hh = 0; hh < 2; hh++) {
        kk[hh][0] = *(const bf16x8*)&Ksw[(hh * 16 + lm) * 32 + (quad ^ rk) * 8];
        kk[hh][1] = *(const bf16x8*)&Ksw[1024 + (hh * 16 + lm) * 32 + (quad ^ rk) * 8];
      }
      f32x4 S[2][2];
#pragma unroll
      for (int s = 0; s < 2; s++)
#pragma unroll
        for (int hh = 0; hh < 2; hh++) {
          f32x4 a = zero;
          a = __builtin_amdgcn_mfma_f32_16x16x32_bf16(kk[hh][0], qf[s][0], a, 0, 0, 0);
          a = __builtin_amdgcn_mfma_f32_16x16x32_bf16(kk[hh][1], qf[s][1], a, 0, 0, 0);
          S[s][hh] = a;
        }
      __builtin_amdgcn_sched_barrier(0);  // pin: QK before K-restage
      const bool more = (t + 1 < ei);
      if (more) {
        stageK(t + 1);                                    // K region dead now
        asm volatile("s_waitcnt vmcnt(4)" ::: "memory");  // V(t) landed
      } else {
        asm volatile("s_waitcnt vmcnt(0)" ::: "memory");
      }
      V8 vf[4];
#pragma unroll
      for (int j = 0; j < 4; j++) {
        vf[j].q.lo = *(const u64*)&Vsw[(j * 16 + lm) * 32 +
                                       (((quad >> 1)) ^ rk) * 8 + (quad & 1) * 4];
        vf[j].q.hi = *(const u64*)&Vsw[(j * 16 + lm) * 32 +
                                       (((quad >> 1) | 2) ^ rk) * 8 + (quad & 1) * 4];
      }
      const bool maskT = (t == qb);
#pragma unroll
      for (int s = 0; s < 2; s++) {
        float p[2][4];
#pragma unroll
        for (int hh = 0; hh < 2; hh++)
#pragma unroll
          for (int r = 0; r < 4; r++)
            p[hh][r] = exp2_raw(S[s][hh][r]);  // scale pre-folded into Q
        if (maskT) {
#pragma unroll
          for (int hh = 0; hh < 2; hh++)
#pragma unroll
            for (int r = 0; r < 4; r++)
              if (hh * 16 + quad * 4 + r > s * 16 + lm) p[hh][r] = 0.f;
        }
        unsigned pk[4];
        pk[0] = cvt_pk_bf16(p[0][0], p[0][1]);
        pk[1] = cvt_pk_bf16(p[0][2], p[0][3]);
        pk[2] = cvt_pk_bf16(p[1][0], p[1][1]);
        pk[3] = cvt_pk_bf16(p[1][2], p[1][3]);
        const bf16x8 pf = *(const bf16x8*)pk;
        al[s] = __builtin_amdgcn_mfma_f32_16x16x32_bf16(ones, pf, al[s], 0, 0, 0);
#pragma unroll
        for (int j = 0; j < 4; j++)
          ot[s][j] = __builtin_amdgcn_mfma_f32_16x16x32_bf16(vf[j].v, pf, ot[s][j], 0, 0, 0);
      }
      __builtin_amdgcn_sched_barrier(0);  // pin: PV before V-restage
      if (more) stageV(t + 1);            // V region dead now
    }

    __syncthreads();  // ALL waves done staging/reading before Olds overwrite

#pragma unroll
    for (int s = 0; s < 2; s++)
#pragma unroll
      for (int j = 0; j < 4; j++)
        *(f32x4*)&Olds[wave][s * 16 + lm][j * 16 + quad * 4] = ot[s][j];
    if (quad == 0) {
      Llds[wave][0][lm] = al[0][0];  // full k-range sum via ones-MFMA
      Llds[wave][1][lm] = al[1][0];
    }
    __syncthreads();
    const int q = tid >> 3;
    const int e0 = (tid & 7) * 8;
    f32x4 oa = zero, obv = zero;
#pragma unroll
    for (int w = 0; w < 4; w++) {
      oa += *(const f32x4*)&Olds[w][q][e0];
      obv += *(const f32x4*)&Olds[w][q][e0 + 4];
    }
    const float lt = Llds[0][q >> 4][q & 15] + Llds[1][q >> 4][q & 15] +
                     Llds[2][q >> 4][q & 15] + Llds[3][q >> 4][q & 15];
    const float linv = 1.f / lt;
    const size_t rowbase = ((size_t)(b * 2048 + qw0 + q)) * 1024 + h * 64 + e0;
    float xv[8];
    if (f32in) {
      const float* xf = (const float*)xres + rowbase;
      const float4 u0 = *(const float4*)xf;
      const float4 u1 = *(const float4*)(xf + 4);
      xv[0] = u0.x; xv[1] = u0.y; xv[2] = u0.z; xv[3] = u0.w;
      xv[4] = u1.x; xv[5] = u1.y; xv[6] = u1.z; xv[7] = u1.w;
    } else {
      const u16x8 u = *(const u16x8*)((const u16*)xres + rowbase);
#pragma unroll
      for (int k = 0; k < 8; k++) xv[k] = bf2f(u[k]);
    }
    u16x8 o8;
#pragma unroll
    for (int k = 0; k < 4; k++) o8[k] = f2bf(xv[k] + oa[k] * linv);
#pragma unroll
    for (int k = 0; k < 4; k++) o8[4 + k] = f2bf(xv[4 + k] + obv[k] * linv);
    *(u16x8*)&x2[rowbase] = o8;
    __syncthreads();
  }
}

// ---------------- LayerNorm (ddof=1, eps=1e-5), raw dual-dtype inputs ------
__launch_bounds__(256)
__global__ void ln_kernel(const void* __restrict__ x, const void* __restrict__ gamma,
                          const void* __restrict__ beta, u16* __restrict__ out,
                          const int* __restrict__ flag, int xraw) {
  const size_t row = blockIdx.x;
  const int tid = threadIdx.x;
  const int f = *flag;
  const int fx = xraw ? f : 0;
  float v0, v1, v2, v3;
  if (fx) {
    const float4 v = *((const float4*)x + row * 256 + tid);
    v0 = v.x; v1 = v.y; v2 = v.z; v3 = v.w;
  } else {
    const ushort4 u = *((const ushort4*)x + row * 256 + tid);
    v0 = bf2f(u.x); v1 = bf2f(u.y); v2 = bf2f(u.z); v3 = bf2f(u.w);
  }
  float s = v0 + v1 + v2 + v3;
  float sq = v0 * v0 + v1 * v1 + v2 * v2 + v3 * v3;
#pragma unroll
  for (int off = 32; off > 0; off >>= 1) {
    s += __shfl_down(s, off);
    sq += __shfl_down(sq, off);
  }
  __shared__ float ss[4], ssq[4];
  if ((tid & 63) == 0) { ss[tid >> 6] = s; ssq[tid >> 6] = sq; }
  __syncthreads();
  s = ss[0] + ss[1] + ss[2] + ss[3];
  sq = ssq[0] + ssq[1] + ssq[2] + ssq[3];
  const float mean = s * (1.f / 1024.f);
  const float var = (sq - 1024.f * mean * mean) * (1.f / 1023.f);
  const float rs = rsqrtf(var + 1e-5f);
  const int c0 = tid * 4;
  ushort4 o;
  o.x = f2bf(ld_f(gamma, c0 + 0, f) * (v0 - mean) * rs + ld_f(beta, c0 + 0, f));
  o.y = f2bf(ld_f(gamma, c0 + 1, f) * (v1 - mean) * rs + ld_f(beta, c0 + 1, f));
  o.z = f2bf(ld_f(gamma, c0 + 2, f) * (v2 - mean) * rs + ld_f(beta, c0 + 2, f));
  o.w = f2bf(ld_f(gamma, c0 + 3, f) * (v3 - mean) * rs + ld_f(beta, c0 + 3, f));
  *(ushort4*)&out[row * 1024 + tid * 4] = o;
}

extern "C" void kernel_launch(void* const* d_in, const int* in_sizes, int n_in,
                              void* d_out, int out_size, void* d_ws, size_t ws_size,
                              hipStream_t stream) {
  const void* x      = d_in[0];
  const void* Wq     = d_in[1];
  const void* Wk     = d_in[2];
  const void* Wv     = d_in[3];
  const void* W1     = d_in[4];
  const void* b1     = d_in[5];
  const void* W2     = d_in[6];
  const void* b2     = d_in[7];
  const void* gamma1 = d_in[8];
  const void* beta1  = d_in[9];
  const void* gamma2 = d_in[10];
  const void* beta2  = d_in[11];
  u16* ws = (u16*)d_ws;

  const size_t M4 = 4194304;
  u16* h   = ws;            // slot 0 (later: ff1 spans 0-3)
  u16* Qb  = ws + 1 * M4;   // slot 1
  u16* Kb  = ws + 2 * M4;   // slot 2
  u16* Vtb = ws + 3 * M4;   // slot 3
  u16* WTq = ws + 4 * M4;   // slot 4 (later: x2)
  u16* x2  = ws + 4 * M4;
  u16* h2  = ws + 5 * M4;   // slot 5 (later: FFN2 partial P0)
  u16* W1T = ws + 6 * M4;   // slot 6 (later: FFN2 partial P1)
  u16* W2T = ws + 7 * M4;   // slot 7
  u16* ff1 = ws;            // slots 0-3
  u16* P0  = ws + 5 * M4;   // bf16 partial kq=0 (h2 dead after FFN1)
  u16* P1  = ws + 6 * M4;   // bf16 partial kq=1 (W1T dead after FFN1)
  int* flag = (int*)(ws + 8 * M4 + 9216);

  // prep: transposes + dtype sniff + FUSED ln1 (blocks 2816..6911)
  prep_kernel<<<6912, 256, 0, stream>>>((const u16*)x, Wq, Wk, Wv, W1, W2,
                                        WTq, W1T, W2T, gamma1, beta1, h, flag);
  // 256x128 tiles, 8 waves: 384 blocks (n-tiles 24 -> sxp 3)
  gemm_bt<0, 4, 2, false><<<384, 512, 0, stream>>>(h, WTq, 1024, 1024, 24, 3072,
                                                   nullptr, nullptr, nullptr,
                                                   Qb, Kb, Vtb, flag);
  // attn v15: split-phase single-buffer pipelining, 16 waves/CU
  attn_mfma<<<1024, 256, 0, stream>>>(Qb, Kb, Vtb, x, flag, x2);
  ln_kernel<<<4096, 256, 0, stream>>>(x2, gamma2, beta2, h2, flag, 0);
  // 256x128 tiles, 8 waves: 512 blocks (n-tiles 32 -> sxp 4)
  gemm_bt<1, 4, 2, false><<<512, 512, 0, stream>>>(h2, W1T, 1024, 1024, 32, 4096,
                                                   b1, nullptr, ff1,
                                                   nullptr, nullptr, nullptr, flag);
  // FFN2: 128x128 tiles, grid split-K2 -> 512 blocks (2/CU), bf16 partials
  gemm_bt<3, 2, 2, false><<<512, 256, 0, stream>>>(ff1, W2T, 2048, 4096, 8, 1024,
                                                   nullptr, nullptr, nullptr,
                                                   P0, P1, nullptr, flag);
  // reduce: out = P0 + P1 + b2 + x2
  ffn2_reduce<<<2048, 256, 0, stream>>>(P0, P1, b2, x2, d_out, flag);
}

// Round 14
// 308.696 us; speedup vs baseline: 1.0425x; 1.0267x over previous
//
#include <hip/hip_runtime.h>

typedef unsigned short u16;
typedef __bf16 bf16;
typedef __attribute__((ext_vector_type(8))) __bf16 bf16x8;
typedef __attribute__((ext_vector_type(4))) float f32x4;
typedef __attribute__((ext_vector_type(8))) unsigned short u16x8;
typedef unsigned long long u64;

__device__ __forceinline__ float bf2f(u16 h) {
  return __uint_as_float(((unsigned int)h) << 16);
}
__device__ __forceinline__ u16 f2bf(float f) {
  unsigned int u = __float_as_uint(f);
  return (u16)((u + 0x7fffu + ((u >> 16) & 1u)) >> 16);
}
__device__ __forceinline__ u16 ld_cv(const void* p, size_t i, int f32) {
  return f32 ? f2bf(((const float*)p)[i]) : ((const u16*)p)[i];
}
__device__ __forceinline__ float ld_f(const void* p, size_t i, int f32) {
  return f32 ? ((const float*)p)[i] : bf2f(((const u16*)p)[i]);
}
__device__ __forceinline__ void async16(const u16* g, u16* l) {
  __builtin_amdgcn_global_load_lds(
      (const __attribute__((address_space(1))) unsigned int*)g,
      (__attribute__((address_space(3))) unsigned int*)l, 16, 0, 0);
}
// raw v_exp_f32: D = 2^S0 (scale pre-folded into Q at the QKV epilogue)
__device__ __forceinline__ float exp2_raw(float x) {
  float r;
  asm("v_exp_f32 %0, %1" : "=v"(r) : "v"(x));
  return r;
}
// packed f32x2 -> bf16x2 (RNE); dst.lo = cvt(a), dst.hi = cvt(b)
__device__ __forceinline__ unsigned cvt_pk_bf16(float a, float b) {
  unsigned r;
  asm("v_cvt_pk_bf16_f32 %0, %1, %2" : "=v"(r) : "v"(a), "v"(b));
  return r;
}

// ---- mega-prep: weight transposes + fused dtype sniff + fused ln1 --------
// Blocks 0..2815: weight transposes (VECTORIZED: float4/ushort4 global
// loads, ushort4 global stores; LDS tile scalar at stride-65, conflict-free).
// Blocks 2816..6911: LayerNorm1 on row (bid-2816). Every block computes the
// dtype flag locally; block 0 publishes it for downstream kernels.
__global__ void prep_kernel(const u16* __restrict__ x,
                            const void* __restrict__ Wq, const void* __restrict__ Wk,
                            const void* __restrict__ Wv, const void* __restrict__ W1,
                            const void* __restrict__ W2,
                            u16* __restrict__ WTq, u16* __restrict__ W1T,
                            u16* __restrict__ W2T,
                            const void* __restrict__ gamma1,
                            const void* __restrict__ beta1,
                            u16* __restrict__ hOut, int* __restrict__ flag) {
  __shared__ u16 tile[64][65];
  __shared__ int sm[4];
  __shared__ float ss[4], ssq[4];
  const int tid = threadIdx.x;
  int me = 0;
#pragma unroll
  for (int j = 0; j < 4; j++) {
    const u16 v = x[(tid * 4 + j) * 2];
    const int e = (v >> 7) & 0xFF;
    me = me > e ? me : e;
  }
#pragma unroll
  for (int off = 32; off > 0; off >>= 1) {
    const int o = __shfl_down(me, off);
    me = me > o ? me : o;
  }
  if ((tid & 63) == 0) sm[tid >> 6] = me;
  __syncthreads();
  const int a01 = sm[0] > sm[1] ? sm[0] : sm[1];
  const int a23 = sm[2] > sm[3] ? sm[2] : sm[3];
  const int f = ((a01 > a23 ? a01 : a23) >= 140) ? 1 : 0;
  if (blockIdx.x == 0 && tid == 0) *flag = f;

  const int bid = blockIdx.x;
  if (bid >= 2816) {
    // ---- fused LayerNorm1 (x dtype follows f) ----
    const size_t row = bid - 2816;
    float v0, v1, v2, v3;
    if (f) {
      const float4 v = *((const float4*)x + row * 256 + tid);
      v0 = v.x; v1 = v.y; v2 = v.z; v3 = v.w;
    } else {
      const ushort4 u = *((const ushort4*)x + row * 256 + tid);
      v0 = bf2f(u.x); v1 = bf2f(u.y); v2 = bf2f(u.z); v3 = bf2f(u.w);
    }
    float s = v0 + v1 + v2 + v3;
    float sq = v0 * v0 + v1 * v1 + v2 * v2 + v3 * v3;
#pragma unroll
    for (int off = 32; off > 0; off >>= 1) {
      s += __shfl_down(s, off);
      sq += __shfl_down(sq, off);
    }
    if ((tid & 63) == 0) { ss[tid >> 6] = s; ssq[tid >> 6] = sq; }
    __syncthreads();
    s = ss[0] + ss[1] + ss[2] + ss[3];
    sq = ssq[0] + ssq[1] + ssq[2] + ssq[3];
    const float mean = s * (1.f / 1024.f);
    const float var = (sq - 1024.f * mean * mean) * (1.f / 1023.f);
    const float rs = rsqrtf(var + 1e-5f);
    const int c0 = tid * 4;
    ushort4 o;
    o.x = f2bf(ld_f(gamma1, c0 + 0, f) * (v0 - mean) * rs + ld_f(beta1, c0 + 0, f));
    o.y = f2bf(ld_f(gamma1, c0 + 1, f) * (v1 - mean) * rs + ld_f(beta1, c0 + 1, f));
    o.z = f2bf(ld_f(gamma1, c0 + 2, f) * (v2 - mean) * rs + ld_f(beta1, c0 + 2, f));
    o.w = f2bf(ld_f(gamma1, c0 + 3, f) * (v3 - mean) * rs + ld_f(beta1, c0 + 3, f));
    *(ushort4*)&hOut[row * 1024 + tid * 4] = o;
    return;
  }

  // ---- transpose: unified vectorized 64x64 tile path ----
  const void* src;
  u16* dst;
  int R, C, tcc, trr, rowbase;
  size_t sb = 0;
  if (bid < 768) {
    const int bx = bid & 15, wh = bid >> 4;
    const int w = wh >> 4, hh = wh & 15;
    trr = bx * 64;
    src = (w == 0) ? Wq : ((w == 1) ? Wk : Wv);
    sb = (size_t)hh * 65536;
    dst = WTq; R = 1024; C = 64; tcc = 0;
    rowbase = w * 1024 + hh * 64;
  } else if (bid < 1792) {
    const int j = bid - 768;
    src = W1; dst = W1T; R = 1024; C = 4096;
    tcc = (j & 63) * 64; trr = (j >> 6) * 64;
    rowbase = tcc;
  } else {
    const int j = bid - 1792;
    src = W2; dst = W2T; R = 4096; C = 1024;
    tcc = (j & 15) * 64; trr = (j >> 4) * 64;
    rowbase = tcc;
  }
  const int rr = tid >> 4, c4 = (tid & 15) * 4;
#pragma unroll
  for (int p = 0; p < 4; p++) {
    const int r = p * 16 + rr;
    const size_t off = sb + (size_t)(trr + r) * C + tcc + c4;
    if (f) {
      const float4 v = *(const float4*)((const float*)src + off);
      tile[r][c4 + 0] = f2bf(v.x);
      tile[r][c4 + 1] = f2bf(v.y);
      tile[r][c4 + 2] = f2bf(v.z);
      tile[r][c4 + 3] = f2bf(v.w);
    } else {
      const ushort4 u = *(const ushort4*)((const u16*)src + off);
      tile[r][c4 + 0] = u.x;
      tile[r][c4 + 1] = u.y;
      tile[r][c4 + 2] = u.z;
      tile[r][c4 + 3] = u.w;
    }
  }
  __syncthreads();
#pragma unroll
  for (int p = 0; p < 4; p++) {
    const int wrow = p * 16 + rr;
    ushort4 o;
    o.x = tile[c4 + 0][wrow];
    o.y = tile[c4 + 1][wrow];
    o.z = tile[c4 + 2][wrow];
    o.w = tile[c4 + 3][wrow];
    *(ushort4*)&dst[(size_t)(rowbase + wrow) * R + trr + c4] = o;
  }
}

// ---------------- GEMM: C[m][n] = sum_k A[m][k] * BT[n][k] ----------------
// Chunk-XOR LDS swizzle (T2, rule #21). EPI==3: FFN2 split-K2 partials.
// EPI==0: Q output is pre-scaled by log2(e)/32 so attn uses raw v_exp_f32.
template <int EPI, int WR, int WC, bool MS>
__launch_bounds__(WR * WC * 64)
__global__ void gemm_bt(const u16* __restrict__ A, const u16* __restrict__ B,
                        int K, int KLD, int NX, int N,
                        const void* __restrict__ bias, const u16* __restrict__ res,
                        void* __restrict__ out,
                        u16* __restrict__ Qo, u16* __restrict__ Ko, u16* __restrict__ Vto,
                        const int* __restrict__ flag) {
  constexpr int BM = WR * 64, BN = WC * 64, T = WR * WC * 64;
  constexpr int RPA = T / 4;
  constexpr int RAH = BM / RPA;
  constexpr int RBH = BN / RPA;
  __shared__ __align__(16) u16 As[BM * 64];
  __shared__ __align__(16) u16 Bs[BN * 64];
  const int tid = threadIdx.x;
  const int bid = blockIdx.x;
  const int sxp = NX >> 3;
  const int xcd = bid & 7, j9 = bid >> 3;
  int m0, n0, koff = 0, khb = 0;
  if (EPI == 3) {
    m0 = (xcd * 4 + (j9 & 3)) * BM;
    n0 = ((j9 >> 2) & 7) * BN;
    khb = (j9 >> 5) & 1;
    koff = khb * K;
  } else if (MS) {
    m0 = (xcd * sxp + j9 % sxp) * BM;
    n0 = (j9 / sxp) * BN;
  } else {
    n0 = (xcd * sxp + j9 % sxp) * BN;
    m0 = (j9 / sxp) * BM;
  }
  const int wave = tid >> 6, lane = tid & 63;
  const int wm = (wave / WC) * 64, wn = (wave % WC) * 64;
  const int lm = lane & 15, lq = lane >> 4;
  const int fb = (EPI == 1 || EPI == 2) ? *flag : 0;

  const f32x4 zero = {0.f, 0.f, 0.f, 0.f};
  f32x4 acc[4][4];
#pragma unroll
  for (int i = 0; i < 4; i++)
#pragma unroll
    for (int j = 0; j < 4; j++) acc[i][j] = zero;

  const int ar = tid >> 2;
  const int ac = ((tid & 3) ^ ((tid >> 3) & 3)) * 8;
  const u16* Ag = A + (size_t)(m0 + ar) * KLD + koff + ac;
  const u16* Bg = B + (size_t)(n0 + ar) * KLD + koff + ac;
  u16* AsP = &As[tid * 8];
  u16* BsP = &Bs[tid * 8];
  const int rq = (lq ^ ((lm >> 1) & 3)) * 8;

  for (int k0 = 0; k0 < K; k0 += 64) {
#pragma unroll
    for (int hh = 0; hh < 2; hh++) {
#pragma unroll
      for (int c = 0; c < RAH; c++)
        async16(Ag + k0 + hh * 32 + (size_t)c * RPA * KLD,
                AsP + hh * BM * 32 + c * RPA * 32);
#pragma unroll
      for (int c = 0; c < RBH; c++)
        async16(Bg + k0 + hh * 32 + (size_t)c * RPA * KLD,
                BsP + hh * BN * 32 + c * RPA * 32);
    }
    __syncthreads();
    bf16x8 a0[4], a1[4], b0[4], b1[4];
#pragma unroll
    for (int i = 0; i < 4; i++) {
      a0[i] = *(const bf16x8*)&As[(wm + i * 16 + lm) * 32 + rq];
      a1[i] = *(const bf16x8*)&As[BM * 32 + (wm + i * 16 + lm) * 32 + rq];
    }
#pragma unroll
    for (int i = 0; i < 4; i++) {
      b0[i] = *(const bf16x8*)&Bs[(wn + i * 16 + lm) * 32 + rq];
      b1[i] = *(const bf16x8*)&Bs[BN * 32 + (wn + i * 16 + lm) * 32 + rq];
    }
#pragma unroll
    for (int i = 0; i < 4; i++)
#pragma unroll
      for (int j = 0; j < 4; j++) {
        acc[i][j] = __builtin_amdgcn_mfma_f32_16x16x32_bf16(a0[i], b0[j], acc[i][j], 0, 0, 0);
        acc[i][j] = __builtin_amdgcn_mfma_f32_16x16x32_bf16(a1[i], b1[j], acc[i][j], 0, 0, 0);
      }
    __syncthreads();
  }

  if (EPI == 0) {
#pragma unroll
    for (int i = 0; i < 4; i++) {
      const int row0 = m0 + wm + i * 16 + lq * 4;
      const int bb = row0 >> 11, t0 = row0 & 2047;
#pragma unroll
      for (int j = 0; j < 4; j++) {
        const int col = n0 + wn + j * 16 + lm;
        const int w = col >> 10, nn = col & 1023;
        const int hh = nn >> 6, e = nn & 63;
        if (w == 2) {
          ushort4 v4;
          v4.x = f2bf(acc[i][j][0]);
          v4.y = f2bf(acc[i][j][1]);
          v4.z = f2bf(acc[i][j][2]);
          v4.w = f2bf(acc[i][j][3]);
          *(ushort4*)&Vto[(((size_t)(bb * 16 + hh)) * 64 + e) * 2048 + t0] = v4;
        } else {
          u16* dst = (w == 0) ? Qo : Ko;
          const float qs = (w == 0) ? 0.04508422f : 1.0f;  // log2(e)/32 folded into Q
#pragma unroll
          for (int r = 0; r < 4; r++)
            dst[(((size_t)(bb * 16 + hh)) * 2048 + t0 + r) * 64 + e] =
                f2bf(acc[i][j][r] * qs);
        }
      }
    }
  } else if (EPI == 3) {
    u16* P = khb ? Ko : Qo;
#pragma unroll
    for (int i = 0; i < 4; i++) {
#pragma unroll
      for (int r = 0; r < 4; r++) {
        const int row = m0 + wm + i * 16 + lq * 4 + r;
#pragma unroll
        for (int j = 0; j < 4; j++) {
          const int col = n0 + wn + j * 16 + lm;
          P[(size_t)row * N + col] = f2bf(acc[i][j][r]);
        }
      }
    }
  } else {
#pragma unroll
    for (int i = 0; i < 4; i++) {
#pragma unroll
      for (int r = 0; r < 4; r++) {
        const int row = m0 + wm + i * 16 + lq * 4 + r;
#pragma unroll
        for (int j = 0; j < 4; j++) {
          const int col = n0 + wn + j * 16 + lm;
          const float c = acc[i][j][r];
          if (EPI == 1) {
            const float v = c + ld_f(bias, col, fb);
            ((u16*)out)[(size_t)row * N + col] = f2bf(v > 0.f ? v : 0.f);
          } else {
            const float v = c + ld_f(bias, col, fb) + bf2f(res[(size_t)row * N + col]);
            if (fb)
              ((float*)out)[(size_t)row * N + col] = v;
            else
              ((u16*)out)[(size_t)row * N + col] = f2bf(v);
          }
        }
      }
    }
  }
}

// ---------------- FFN2 split-K reduce: out = P0 + P1 + bias + res ----------
__launch_bounds__(256)
__global__ void ffn2_reduce(const u16* __restrict__ P0, const u16* __restrict__ P1,
                            const void* __restrict__ bias, const u16* __restrict__ res,
                            void* __restrict__ out, const int* __restrict__ flag) {
  const int f = *flag;
  const size_t i0 = ((size_t)blockIdx.x * 256 + threadIdx.x) * 8;
  const int col = (int)(i0 & 1023);
  const u16x8 a8 = *(const u16x8*)(P0 + i0);
  const u16x8 b8 = *(const u16x8*)(P1 + i0);
  const u16x8 r8 = *(const u16x8*)(res + i0);
  float v[8];
#pragma unroll
  for (int k = 0; k < 8; k++)
    v[k] = bf2f(a8[k]) + bf2f(b8[k]) + ld_f(bias, col + k, f) + bf2f(r8[k]);
  if (f) {
    float4 o0 = {v[0], v[1], v[2], v[3]};
    float4 o1 = {v[4], v[5], v[6], v[7]};
    *(float4*)((float*)out + i0) = o0;
    *(float4*)((float*)out + i0 + 4) = o1;
  } else {
    u16x8 o8;
#pragma unroll
    for (int k = 0; k < 8; k++) o8[k] = f2bf(v[k]);
    *(u16x8*)((u16*)out + i0) = o8;
  }
}

// ---------------- MFMA flash attention v15: split-phase pipelined ----------
// (measured ~50us; best of all structures tried this session)
__launch_bounds__(256)
__global__ void attn_mfma(const u16* __restrict__ Q, const u16* __restrict__ K,
                          const u16* __restrict__ Vt, const void* __restrict__ xres,
                          const int* __restrict__ flag, u16* __restrict__ x2) {
  __shared__ __align__(16) unsigned char smem[35328];
  const int tid = threadIdx.x;
  const int wave = tid >> 6, lane = tid & 63;
  const int lm = lane & 15, quad = lane >> 4;
  const int bid = blockIdx.x;
  const int xcd = bid & 7, jj = bid >> 3;
  const int bh = xcd + 8 * (jj & 3);
  const int pair = jj >> 2;  // 0..31
  const int b = bh >> 4, h = bh & 15;
  const int f32in = *flag;

  u16* stw = (u16*)smem + wave * 4096;  // 8KB per wave
  u16* Ksw = stw;                        // [half][32 rows][4 chunks x 8]
  u16* Vsw = stw + 2048;                 // [64 rows][4 chunks x 8]
  float (*Olds)[32][68] = (float(*)[32][68])smem;          // 34816 B
  float (*Llds)[2][16] = (float(*)[2][16])(smem + 34816);  // 512 B

  const u16* Kbh = K + (size_t)bh * 131072;
  const u16* Vbh = Vt + (size_t)bh * 131072;
  const f32x4 zero = {0.f, 0.f, 0.f, 0.f};
  const int srow = lane >> 2;
  const int sch2 = (((lane & 3) ^ ((srow >> 1) & 3))) * 8;
  const int rk = (lm >> 1) & 3;

  union V8 { bf16x8 v; struct { u64 lo, hi; } q; };
  u16x8 ob;
#pragma unroll
  for (int k = 0; k < 8; k++) ob[k] = 0x3F80;
  const bf16x8 ones = *(const bf16x8*)&ob;

  auto stageK = [&](int t) {
    const int ks = t * 32;
#pragma unroll
    for (int hh2 = 0; hh2 < 2; hh2++)
#pragma unroll
      for (int c = 0; c < 2; c++)
        async16(Kbh + (size_t)(ks + c * 16 + srow) * 64 + hh2 * 32 + sch2,
                Ksw + hh2 * 1024 + c * 512 + lane * 8);
  };
  auto stageV = [&](int t) {
    const int ks = t * 32;
#pragma unroll
    for (int c = 0; c < 4; c++)
      async16(Vbh + (size_t)(c * 16 + srow) * 2048 + ks + sch2,
              Vsw + c * 512 + lane * 8);
  };

#pragma unroll 1
  for (int phase = 0; phase < 2; phase++) {
    const int qb = phase ? (63 - pair) : pair;
    const int qw0 = qb * 32;

    bf16x8 qf[2][2];
#pragma unroll
    for (int s = 0; s < 2; s++) {
      const u16* Qp = Q + ((size_t)bh * 2048 + qw0 + s * 16 + lm) * 64 + quad * 8;
      qf[s][0] = *(const bf16x8*)Qp;
      qf[s][1] = *(const bf16x8*)(Qp + 32);
    }
    __builtin_amdgcn_s_waitcnt(0x0F70);  // qf resident; vm queue empty
    f32x4 ot[2][4];
    f32x4 al[2];
#pragma unroll
    for (int s = 0; s < 2; s++) {
#pragma unroll
      for (int j = 0; j < 4; j++) ot[s][j] = zero;
      al[s] = zero;
    }

    const int nt = qb + 1;
    const int si = (nt * wave) >> 2;
    const int ei = (nt * (wave + 1)) >> 2;

    if (si < ei) { stageK(si); stageV(si); }  // 4 + 4 in flight (K older)

#pragma unroll 1
    for (int t = si; t < ei; t++) {
      asm volatile("s_waitcnt vmcnt(4)" ::: "memory");  // K(t) landed
      bf16x8 kk[2][2];
#pragma unroll
      for (int hh = 0; hh < 2; hh++) {
        kk[hh][0] = *(const bf16x8*)&Ksw[(hh * 16 + lm) * 32 + (quad ^ rk) * 8];
        kk[hh][1] = *(const bf16x8*)&Ksw[1024 + (hh * 16 + lm) * 32 + (quad ^ rk) * 8];
      }
      f32x4 S[2][2];
#pragma unroll
      for (int s = 0; s < 2; s++)
#pragma unroll
        for (int hh = 0; hh < 2; hh++) {
          f32x4 a = zero;
          a = __builtin_amdgcn_mfma_f32_16x16x32_bf16(kk[hh][0], qf[s][0], a, 0, 0, 0);
          a = __builtin_amdgcn_mfma_f32_16x16x32_bf16(kk[hh][1], qf[s][1], a, 0, 0, 0);
          S[s][hh] = a;
        }
      __builtin_amdgcn_sched_barrier(0);  // pin: QK before K-restage
      const bool more = (t + 1 < ei);
      if (more) {
        stageK(t + 1);                                    // K region dead now
        asm volatile("s_waitcnt vmcnt(4)" ::: "memory");  // V(t) landed
      } else {
        asm volatile("s_waitcnt vmcnt(0)" ::: "memory");
      }
      V8 vf[4];
#pragma unroll
      for (int j = 0; j < 4; j++) {
        vf[j].q.lo = *(const u64*)&Vsw[(j * 16 + lm) * 32 +
                                       (((quad >> 1)) ^ rk) * 8 + (quad & 1) * 4];
        vf[j].q.hi = *(const u64*)&Vsw[(j * 16 + lm) * 32 +
                                       (((quad >> 1) | 2) ^ rk) * 8 + (quad & 1) * 4];
      }
      const bool maskT = (t == qb);
#pragma unroll
      for (int s = 0; s < 2; s++) {
        float p[2][4];
#pragma unroll
        for (int hh = 0; hh < 2; hh++)
#pragma unroll
          for (int r = 0; r < 4; r++)
            p[hh][r] = exp2_raw(S[s][hh][r]);  // scale pre-folded into Q
        if (maskT) {
#pragma unroll
          for (int hh = 0; hh < 2; hh++)
#pragma unroll
            for (int r = 0; r < 4; r++)
              if (hh * 16 + quad * 4 + r > s * 16 + lm) p[hh][r] = 0.f;
        }
        unsigned pk[4];
        pk[0] = cvt_pk_bf16(p[0][0], p[0][1]);
        pk[1] = cvt_pk_bf16(p[0][2], p[0][3]);
        pk[2] = cvt_pk_bf16(p[1][0], p[1][1]);
        pk[3] = cvt_pk_bf16(p[1][2], p[1][3]);
        const bf16x8 pf = *(const bf16x8*)pk;
        al[s] = __builtin_amdgcn_mfma_f32_16x16x32_bf16(ones, pf, al[s], 0, 0, 0);
#pragma unroll
        for (int j = 0; j < 4; j++)
          ot[s][j] = __builtin_amdgcn_mfma_f32_16x16x32_bf16(vf[j].v, pf, ot[s][j], 0, 0, 0);
      }
      __builtin_amdgcn_sched_barrier(0);  // pin: PV before V-restage
      if (more) stageV(t + 1);            // V region dead now
    }

    __syncthreads();  // ALL waves done staging/reading before Olds overwrite

#pragma unroll
    for (int s = 0; s < 2; s++)
#pragma unroll
      for (int j = 0; j < 4; j++)
        *(f32x4*)&Olds[wave][s * 16 + lm][j * 16 + quad * 4] = ot[s][j];
    if (quad == 0) {
      Llds[wave][0][lm] = al[0][0];  // full k-range sum via ones-MFMA
      Llds[wave][1][lm] = al[1][0];
    }
    __syncthreads();
    const int q = tid >> 3;
    const int e0 = (tid & 7) * 8;
    f32x4 oa = zero, obv = zero;
#pragma unroll
    for (int w = 0; w < 4; w++) {
      oa += *(const f32x4*)&Olds[w][q][e0];
      obv += *(const f32x4*)&Olds[w][q][e0 + 4];
    }
    const float lt = Llds[0][q >> 4][q & 15] + Llds[1][q >> 4][q & 15] +
                     Llds[2][q >> 4][q & 15] + Llds[3][q >> 4][q & 15];
    const float linv = 1.f / lt;
    const size_t rowbase = ((size_t)(b * 2048 + qw0 + q)) * 1024 + h * 64 + e0;
    float xv[8];
    if (f32in) {
      const float* xf = (const float*)xres + rowbase;
      const float4 u0 = *(const float4*)xf;
      const float4 u1 = *(const float4*)(xf + 4);
      xv[0] = u0.x; xv[1] = u0.y; xv[2] = u0.z; xv[3] = u0.w;
      xv[4] = u1.x; xv[5] = u1.y; xv[6] = u1.z; xv[7] = u1.w;
    } else {
      const u16x8 u = *(const u16x8*)((const u16*)xres + rowbase);
#pragma unroll
      for (int k = 0; k < 8; k++) xv[k] = bf2f(u[k]);
    }
    u16x8 o8;
#pragma unroll
    for (int k = 0; k < 4; k++) o8[k] = f2bf(xv[k] + oa[k] * linv);
#pragma unroll
    for (int k = 0; k < 4; k++) o8[4 + k] = f2bf(xv[4 + k] + obv[k] * linv);
    *(u16x8*)&x2[rowbase] = o8;
    __syncthreads();
  }
}

// ---------------- LayerNorm (ddof=1, eps=1e-5), raw dual-dtype inputs ------
__launch_bounds__(256)
__global__ void ln_kernel(const void* __restrict__ x, const void* __restrict__ gamma,
                          const void* __restrict__ beta, u16* __restrict__ out,
                          const int* __restrict__ flag, int xraw) {
  const size_t row = blockIdx.x;
  const int tid = threadIdx.x;
  const int f = *flag;
  const int fx = xraw ? f : 0;
  float v0, v1, v2, v3;
  if (fx) {
    const float4 v = *((const float4*)x + row * 256 + tid);
    v0 = v.x; v1 = v.y; v2 = v.z; v3 = v.w;
  } else {
    const ushort4 u = *((const ushort4*)x + row * 256 + tid);
    v0 = bf2f(u.x); v1 = bf2f(u.y); v2 = bf2f(u.z); v3 = bf2f(u.w);
  }
  float s = v0 + v1 + v2 + v3;
  float sq = v0 * v0 + v1 * v1 + v2 * v2 + v3 * v3;
#pragma unroll
  for (int off = 32; off > 0; off >>= 1) {
    s += __shfl_down(s, off);
    sq += __shfl_down(sq, off);
  }
  __shared__ float ss[4], ssq[4];
  if ((tid & 63) == 0) { ss[tid >> 6] = s; ssq[tid >> 6] = sq; }
  __syncthreads();
  s = ss[0] + ss[1] + ss[2] + ss[3];
  sq = ssq[0] + ssq[1] + ssq[2] + ssq[3];
  const float mean = s * (1.f / 1024.f);
  const float var = (sq - 1024.f * mean * mean) * (1.f / 1023.f);
  const float rs = rsqrtf(var + 1e-5f);
  const int c0 = tid * 4;
  ushort4 o;
  o.x = f2bf(ld_f(gamma, c0 + 0, f) * (v0 - mean) * rs + ld_f(beta, c0 + 0, f));
  o.y = f2bf(ld_f(gamma, c0 + 1, f) * (v1 - mean) * rs + ld_f(beta, c0 + 1, f));
  o.z = f2bf(ld_f(gamma, c0 + 2, f) * (v2 - mean) * rs + ld_f(beta, c0 + 2, f));
  o.w = f2bf(ld_f(gamma, c0 + 3, f) * (v3 - mean) * rs + ld_f(beta, c0 + 3, f));
  *(ushort4*)&out[row * 1024 + tid * 4] = o;
}

extern "C" void kernel_launch(void* const* d_in, const int* in_sizes, int n_in,
                              void* d_out, int out_size, void* d_ws, size_t ws_size,
                              hipStream_t stream) {
  const void* x      = d_in[0];
  const void* Wq     = d_in[1];
  const void* Wk     = d_in[2];
  const void* Wv     = d_in[3];
  const void* W1     = d_in[4];
  const void* b1     = d_in[5];
  const void* W2     = d_in[6];
  const void* b2     = d_in[7];
  const void* gamma1 = d_in[8];
  const void* beta1  = d_in[9];
  const void* gamma2 = d_in[10];
  const void* beta2  = d_in[11];
  u16* ws = (u16*)d_ws;

  const size_t M4 = 4194304;
  u16* h   = ws;            // slot 0 (later: ff1 spans 0-3)
  u16* Qb  = ws + 1 * M4;   // slot 1
  u16* Kb  = ws + 2 * M4;   // slot 2
  u16* Vtb = ws + 3 * M4;   // slot 3
  u16* WTq = ws + 4 * M4;   // slot 4 (later: x2)
  u16* x2  = ws + 4 * M4;
  u16* h2  = ws + 5 * M4;   // slot 5 (later: FFN2 partial P0)
  u16* W1T = ws + 6 * M4;   // slot 6 (later: FFN2 partial P1)
  u16* W2T = ws + 7 * M4;   // slot 7
  u16* ff1 = ws;            // slots 0-3
  u16* P0  = ws + 5 * M4;   // bf16 partial kq=0 (h2 dead after FFN1)
  u16* P1  = ws + 6 * M4;   // bf16 partial kq=1 (W1T dead after FFN1)
  int* flag = (int*)(ws + 8 * M4 + 9216);

  // prep: transposes (vectorized) + dtype sniff + fused ln1
  prep_kernel<<<6912, 256, 0, stream>>>((const u16*)x, Wq, Wk, Wv, W1, W2,
                                        WTq, W1T, W2T, gamma1, beta1, h, flag);
  // QKV: 128x128 tiles, 4 waves -> 768 blocks (3/CU, no tail imbalance)
  gemm_bt<0, 2, 2, false><<<768, 256, 0, stream>>>(h, WTq, 1024, 1024, 24, 3072,
                                                   nullptr, nullptr, nullptr,
                                                   Qb, Kb, Vtb, flag);
  // attn v15: split-phase single-buffer pipelining, 16 waves/CU
  attn_mfma<<<1024, 256, 0, stream>>>(Qb, Kb, Vtb, x, flag, x2);
  ln_kernel<<<4096, 256, 0, stream>>>(x2, gamma2, beta2, h2, flag, 0);
  // 256x128 tiles, 8 waves: 512 blocks (n-tiles 32 -> sxp 4)
  gemm_bt<1, 4, 2, false><<<512, 512, 0, stream>>>(h2, W1T, 1024, 1024, 32, 4096,
                                                   b1, nullptr, ff1,
                                                   nullptr, nullptr, nullptr, flag);
  // FFN2: 128x128 tiles, grid split-K2 -> 512 blocks (2/CU), bf16 partials
  gemm_bt<3, 2, 2, false><<<512, 256, 0, stream>>>(ff1, W2T, 2048, 4096, 8, 1024,
                                                   nullptr, nullptr, nullptr,
                                                   P0, P1, nullptr, flag);
  // reduce: out = P0 + P1 + b2 + x2
  ffn2_reduce<<<2048, 256, 0, stream>>>(P0, P1, b2, x2, d_out, flag);
}